// Round 7
// baseline (1351.548 us; speedup 1.0000x reference)
//
#include <hip/hip_runtime.h>
#include <hip/hip_bf16.h>
#include <stdint.h>

#define E_ 8
#define H_ 4096
#define I_ 1792
#define TWOI_ 3584
#define T_ 4096
#define NSLOT_ 8192
#define NS1_ 128   /* H_/32 k-slices */
#define NS2_ 56    /* I_/32 k-slices */

typedef __attribute__((ext_vector_type(4))) float f32x4;
typedef __attribute__((ext_vector_type(8))) short bf16x8;

static __device__ __forceinline__ short f2bf(float f) {
    unsigned u = __builtin_bit_cast(unsigned, f);
    u += 0x7FFF + ((u >> 16) & 1);   // round-to-nearest-even
    return (short)(u >> 16);
}

static __device__ __forceinline__ void gld16(const void* g, void* l) {
    __builtin_amdgcn_global_load_lds(
        (const __attribute__((address_space(1))) void*)g,
        (__attribute__((address_space(3))) void*)l, 16, 0, 0);
}

#define VMW_(n) asm volatile("s_waitcnt vmcnt(" #n ")" ::: "memory")
#define VMW(n) VMW_(n)

// ---------------- routing: build per-expert token lists ----------------
__global__ void route_kernel(const int* __restrict__ eidx,
                             const float* __restrict__ aff,
                             int* __restrict__ cnt, int* __restrict__ off,
                             int* __restrict__ toks, float* __restrict__ wts) {
    __shared__ int scnt[E_];
    __shared__ int soff[E_];
    int tid = threadIdx.x;
    if (tid < E_) scnt[tid] = 0;
    __syncthreads();
    for (int s = tid; s < NSLOT_; s += blockDim.x) {
        atomicAdd(&scnt[eidx[s]], 1);
    }
    __syncthreads();
    if (tid == 0) {
        int acc = 0;
        for (int e = 0; e < E_; ++e) {
            int c = scnt[e];
            cnt[e] = c; off[e] = acc; soff[e] = acc;
            acc += c;
        }
    }
    __syncthreads();
    if (tid < E_) scnt[tid] = soff[tid];
    __syncthreads();
    for (int s = tid; s < NSLOT_; s += blockDim.x) {
        int t = s >> 1;
        int e0 = eidx[t * 2], e1 = eidx[t * 2 + 1];
        float a0 = aff[t * E_ + e0], a1 = aff[t * E_ + e1];
        int k = s & 1;
        int e = k ? e1 : e0;
        float w = (k ? a1 : a0) / (a0 + a1);
        int pos = atomicAdd(&scnt[e], 1);
        toks[pos] = t;
        wts[pos] = w;
    }
}

// ---------------- x f32 -> bf16 ----------------
__global__ __launch_bounds__(256) void xconv_kernel(const float* __restrict__ x,
                                                    short* __restrict__ xb) {
    size_t i = ((size_t)blockIdx.x * 256 + threadIdx.x) * 8;
    float4 f0 = *(const float4*)(x + i);
    float4 f1 = *(const float4*)(x + i + 4);
    bf16x8 v;
    v[0] = f2bf(f0.x); v[1] = f2bf(f0.y); v[2] = f2bf(f0.z); v[3] = f2bf(f0.w);
    v[4] = f2bf(f1.x); v[5] = f2bf(f1.y); v[6] = f2bf(f1.z); v[7] = f2bf(f1.w);
    *(bf16x8*)(xb + i) = v;
}

// ---------------- weight repack -> bf16 (q-128), MFMA k-packet order ----------------
// gu: out[e][y=slice*4+kg][col 3584][8], cols interleaved gate/up at 16-granularity:
//   chunk=col>>4, m=chunk>>1, orig = (chunk&1 ? I_ : 0) + m*16 + (col&15)
__global__ __launch_bounds__(256) void repack_gu_kernel(const int* __restrict__ wq,
                                                        short* __restrict__ out) {
    int e = blockIdx.z;
    int y = blockIdx.y;                           // 0..511
    int col = blockIdx.x * 256 + threadIdx.x;     // repacked col
    int chunk = col >> 4;
    int m = chunk >> 1;
    int orig = ((chunk & 1) ? I_ : 0) + m * 16 + (col & 15);
    const int* src = wq + ((size_t)e * H_ + y * 8) * TWOI_ + orig;
    bf16x8 v;
    #pragma unroll
    for (int j = 0; j < 8; ++j)
        v[j] = f2bf((float)(src[(size_t)j * TWOI_] - 128));
    *(bf16x8*)(out + (((size_t)e * 512 + y) * TWOI_ + col) * 8) = v;
}

__global__ __launch_bounds__(256) void repack_dn_kernel(const int* __restrict__ wq,
                                                        short* __restrict__ out) {
    int e = blockIdx.z;
    int y = blockIdx.y;                           // 0..223
    int col = blockIdx.x * 256 + threadIdx.x;     // 0..4095
    const int* src = wq + ((size_t)e * I_ + y * 8) * H_ + col;
    bf16x8 v;
    #pragma unroll
    for (int j = 0; j < 8; ++j)
        v[j] = f2bf((float)(src[(size_t)j * H_] - 128));
    *(bf16x8*)(out + (((size_t)e * 224 + y) * H_ + col) * 8) = v;
}

// ==================== GEMM1 ring-4 depth-3: 256x256, 8 waves ====================
// phase(s): vmcnt(8) -> barrier -> stage slice s+3 into slot (s+3)&3 -> read slot s&3 -> 32 MFMA
__global__ __launch_bounds__(512, 2) void gemm1x9_kernel(
    const short* __restrict__ xb,       // [T,H] bf16
    const short* __restrict__ wgu,      // [E][512][3584][8] bf16 (y = slice*4+kg)
    const float* __restrict__ scale,    // [E,2I]
    const int* __restrict__ cnt, const int* __restrict__ off,
    const int* __restrict__ toks,
    short* __restrict__ h_ws) {         // [NSLOT,I] bf16
    // XCD-chunked decode: e = xcd; within xcd, by-minor so same-bx blocks run consecutively
    const int id = blockIdx.x;          // 0..3583
    const int e = id & 7;
    const int j = id >> 3;              // 0..447
    const int bx = j >> 5;              // 0..13
    const int by = j & 31;
    int cn = cnt[e];
    int row0 = by * 256;
    if (row0 >= cn) return;
    int base = off[e];

    __shared__ __align__(16) short As[4][4][256][8];   // 64 KB (slot, kg, row, 8)
    __shared__ __align__(16) short Bs[4][4][256][8];   // 64 KB
    __shared__ int stok[256];

    int tid = threadIdx.x;
    if (tid < 256) {
        int r = row0 + tid;
        stok[tid] = toks[base + (r < cn ? r : cn - 1)];
    }
    __syncthreads();

    const int lane = tid & 63;
    const int wid = tid >> 6;
    const int wr128 = (wid >> 2) * 128;
    const int wc64 = (wid & 3) * 64;
    const int fr = lane & 15;
    const int kq = lane >> 4;

    const int srow = tid & 255;
    const int kgo2 = (tid >> 8) * 2;    // 0 or 2

    const short* arow = xb + (size_t)stok[srow] * H_;
    const size_t bstride = (size_t)TWOI_ * 8;
    const short* bsrc = wgu + (size_t)e * 512 * bstride + (size_t)(bx * 256 + srow) * 8;

    bf16x8 av[8], bv[4];
    f32x4 acc[8][4];
    #pragma unroll
    for (int i = 0; i < 8; ++i)
        #pragma unroll
        for (int jj = 0; jj < 4; ++jj) acc[i][jj] = f32x4{0.f, 0.f, 0.f, 0.f};

#define G1_STG(q, slot) do {                                              \
        _Pragma("unroll")                                                 \
        for (int p_ = 0; p_ < 2; ++p_)                                    \
            gld16(arow + (size_t)(q) * 32 + (kgo2 + p_) * 8,              \
                  &As[slot][kgo2 + p_][srow][0]);                         \
        _Pragma("unroll")                                                 \
        for (int p_ = 0; p_ < 2; ++p_)                                    \
            gld16(bsrc + ((size_t)(q) * 4 + kgo2 + p_) * bstride,         \
                  &Bs[slot][kgo2 + p_][srow][0]);                         \
    } while (0)
#define G1_RD(ss) do {                                                    \
        _Pragma("unroll") for (int i_ = 0; i_ < 8; ++i_)                  \
            av[i_] = *(const bf16x8*)&As[ss][kq][wr128 + i_ * 16 + fr][0];\
        _Pragma("unroll") for (int j_ = 0; j_ < 4; ++j_)                  \
            bv[j_] = *(const bf16x8*)&Bs[ss][kq][wc64 + j_ * 16 + fr][0]; \
    } while (0)
#define G1_MM() do {                                                      \
        __builtin_amdgcn_s_setprio(1);                                    \
        _Pragma("unroll") for (int i_ = 0; i_ < 8; ++i_)                  \
        _Pragma("unroll") for (int j_ = 0; j_ < 4; ++j_)                  \
            acc[i_][j_] = __builtin_amdgcn_mfma_f32_16x16x32_bf16(av[i_], bv[j_], acc[i_][j_], 0, 0, 0); \
        __builtin_amdgcn_s_setprio(0);                                    \
    } while (0)
#define G1_PH(ss, q, qs, V, DOSTG) do {                                   \
        VMW(V);                                                           \
        __builtin_amdgcn_s_barrier();                                     \
        __builtin_amdgcn_sched_barrier(0);                                \
        if (DOSTG) G1_STG(q, qs);                                         \
        G1_RD(ss);                                                        \
        G1_MM();                                                          \
    } while (0)

    // prologue: stage slices 0,1,2 (12 loads in flight)
    G1_STG(0, 0); G1_STG(1, 1); G1_STG(2, 2);
    for (int sb = 0; sb < NS1_ - 4; sb += 4) {
        G1_PH(0, sb + 3, 3, 8, 1);
        G1_PH(1, sb + 4, 0, 8, 1);
        G1_PH(2, sb + 5, 1, 8, 1);
        G1_PH(3, sb + 6, 2, 8, 1);
    }
    // peeled tail: s = NS-4..NS-1
    G1_PH(0, NS1_ - 1, 3, 8, 1);
    G1_PH(1, 0, 0, 8, 0);
    G1_PH(2, 0, 0, 4, 0);
    G1_PH(3, 0, 0, 0, 0);
#undef G1_STG
#undef G1_RD
#undef G1_MM
#undef G1_PH

    // epilogue: col pairs (gate,up) of the same 16-channel block m
    const int q4 = lane >> 4;
    #pragma unroll
    for (int cfp = 0; cfp < 2; ++cfp) {
        int m = bx * 8 + (wid & 3) * 2 + cfp;
        int hcol = m * 16 + fr;
        float gs = scale[e * TWOI_ + hcol];
        float us = scale[e * TWOI_ + I_ + hcol];
        #pragma unroll
        for (int rf = 0; rf < 8; ++rf) {
            #pragma unroll
            for (int jj = 0; jj < 4; ++jj) {
                int row = wr128 + rf * 16 + q4 * 4 + jj;
                if (row0 + row < cn) {
                    float gv = acc[rf][cfp * 2][jj] * gs;
                    float uv = acc[rf][cfp * 2 + 1][jj] * us;
                    float s = 1.f / (1.f + __expf(-gv));
                    h_ws[(size_t)(base + row0 + row) * I_ + hcol] = f2bf(gv * s * uv);
                }
            }
        }
    }
}

// ==================== GEMM2 ring-4 depth-3: 256x256, 8 waves ====================
__global__ __launch_bounds__(512, 2) void gemm2x9_kernel(
    const short* __restrict__ h_ws,     // [NSLOT,I] bf16
    const short* __restrict__ wd,       // [E][224][4096][8] bf16
    const float* __restrict__ dscale,   // [E,H]
    const int* __restrict__ cnt, const int* __restrict__ off,
    const int* __restrict__ toks, const float* __restrict__ wts,
    float* __restrict__ out) {          // [T,H]
    const int id = blockIdx.x;          // 0..4095
    const int e = id & 7;
    const int j = id >> 3;              // 0..511
    const int bx = j >> 5;              // 0..15
    const int by = j & 31;
    int cn = cnt[e];
    int row0 = by * 256;
    if (row0 >= cn) return;
    int base = off[e];

    __shared__ __align__(16) short As[4][4][256][8];
    __shared__ __align__(16) short Bs[4][4][256][8];
    __shared__ int stok[256];
    __shared__ float swt[256];

    int tid = threadIdx.x;
    if (tid < 256) {
        int r = row0 + tid;
        int idx = base + (r < cn ? r : cn - 1);
        stok[tid] = toks[idx];
        swt[tid] = (r < cn) ? wts[idx] : 0.f;
    }
    __syncthreads();

    const int lane = tid & 63;
    const int wid = tid >> 6;
    const int wr128 = (wid >> 2) * 128;
    const int wc64 = (wid & 3) * 64;
    const int fr = lane & 15;
    const int kq = lane >> 4;

    const int srow = tid & 255;
    const int kgo2 = (tid >> 8) * 2;

    int rc = row0 + srow; if (rc >= cn) rc = cn - 1;
    const short* arow = h_ws + (size_t)(base + rc) * I_;
    const size_t bstride = (size_t)H_ * 8;
    const short* bsrc = wd + (size_t)e * 224 * bstride + (size_t)(bx * 256 + srow) * 8;

    bf16x8 av[8], bv[4];
    f32x4 acc[8][4];
    #pragma unroll
    for (int i = 0; i < 8; ++i)
        #pragma unroll
        for (int jj = 0; jj < 4; ++jj) acc[i][jj] = f32x4{0.f, 0.f, 0.f, 0.f};

#define G2_STG(q, slot) do {                                              \
        _Pragma("unroll")                                                 \
        for (int p_ = 0; p_ < 2; ++p_)                                    \
            gld16(arow + (size_t)(q) * 32 + (kgo2 + p_) * 8,              \
                  &As[slot][kgo2 + p_][srow][0]);                         \
        _Pragma("unroll")                                                 \
        for (int p_ = 0; p_ < 2; ++p_)                                    \
            gld16(bsrc + ((size_t)(q) * 4 + kgo2 + p_) * bstride,         \
                  &Bs[slot][kgo2 + p_][srow][0]);                         \
    } while (0)
#define G2_RD(ss) do {                                                    \
        _Pragma("unroll") for (int i_ = 0; i_ < 8; ++i_)                  \
            av[i_] = *(const bf16x8*)&As[ss][kq][wr128 + i_ * 16 + fr][0];\
        _Pragma("unroll") for (int j_ = 0; j_ < 4; ++j_)                  \
            bv[j_] = *(const bf16x8*)&Bs[ss][kq][wc64 + j_ * 16 + fr][0]; \
    } while (0)
#define G2_MM() do {                                                      \
        __builtin_amdgcn_s_setprio(1);                                    \
        _Pragma("unroll") for (int i_ = 0; i_ < 8; ++i_)                  \
        _Pragma("unroll") for (int j_ = 0; j_ < 4; ++j_)                  \
            acc[i_][j_] = __builtin_amdgcn_mfma_f32_16x16x32_bf16(av[i_], bv[j_], acc[i_][j_], 0, 0, 0); \
        __builtin_amdgcn_s_setprio(0);                                    \
    } while (0)
#define G2_PH(ss, q, qs, V, DOSTG) do {                                   \
        VMW(V);                                                           \
        __builtin_amdgcn_s_barrier();                                     \
        __builtin_amdgcn_sched_barrier(0);                                \
        if (DOSTG) G2_STG(q, qs);                                         \
        G2_RD(ss);                                                        \
        G2_MM();                                                          \
    } while (0)

    G2_STG(0, 0); G2_STG(1, 1); G2_STG(2, 2);
    for (int sb = 0; sb < NS2_ - 4; sb += 4) {
        G2_PH(0, sb + 3, 3, 8, 1);
        G2_PH(1, sb + 4, 0, 8, 1);
        G2_PH(2, sb + 5, 1, 8, 1);
        G2_PH(3, sb + 6, 2, 8, 1);
    }
    G2_PH(0, NS2_ - 1, 3, 8, 1);
    G2_PH(1, 0, 0, 8, 0);
    G2_PH(2, 0, 0, 4, 0);
    G2_PH(3, 0, 0, 0, 0);
#undef G2_STG
#undef G2_RD
#undef G2_MM
#undef G2_PH

    const int q4 = lane >> 4;
    #pragma unroll
    for (int cf = 0; cf < 4; ++cf) {
        int col = bx * 256 + wc64 + cf * 16 + fr;
        float ds = dscale[e * H_ + col];
        #pragma unroll
        for (int rf = 0; rf < 8; ++rf) {
            #pragma unroll
            for (int jj = 0; jj < 4; ++jj) {
                int row = wr128 + rf * 16 + q4 * 4 + jj;
                if (row0 + row < cn) {
                    float v = acc[rf][cf][jj] * ds * swt[row];
                    atomicAdd(&out[(size_t)stok[row] * H_ + col], v);
                }
            }
        }
    }
}

// ================= fallback path (fused int32 dequant, known-good) =================
__global__ __launch_bounds__(256) void gemm1_kernel(
    const float* __restrict__ x, const int* __restrict__ wq,
    const float* __restrict__ scale,
    const int* __restrict__ cnt, const int* __restrict__ off,
    const int* __restrict__ toks, short* __restrict__ h_ws) {
    int e = blockIdx.z;
    int cn = cnt[e];
    int row0 = blockIdx.y * 128;
    if (row0 >= cn) return;
    int base = off[e];
    int c0 = blockIdx.x * 64;
    __shared__ __align__(16) short As[4][128][8];
    __shared__ __align__(16) short Bg[4][64][8];
    __shared__ __align__(16) short Bu[4][64][8];
    __shared__ int stok[128];
    int tid = threadIdx.x;
    if (tid < 128) {
        int r = row0 + tid;
        stok[tid] = toks[base + (r < cn ? r : 0)];
    }
    __syncthreads();
    const int lane = tid & 63;
    const int wid = tid >> 6;
    const int wrow = (wid >> 1) * 64;
    const int wcc = (wid & 1) * 32;
    const int fr = lane & 15;
    const int kg = lane >> 4;
    f32x4 accg[4][2], accu[4][2];
    #pragma unroll
    for (int i = 0; i < 4; ++i)
        #pragma unroll
        for (int j = 0; j < 2; ++j) {
            accg[i][j] = f32x4{0.f, 0.f, 0.f, 0.f};
            accu[i][j] = f32x4{0.f, 0.f, 0.f, 0.f};
        }
    const int ar = tid & 127;
    const int akg = (tid >> 7) * 2;
    const int bc = tid & 63;
    const int bkg = (tid >> 6) & 3;
    const float* xrow = x + (size_t)stok[ar] * H_;
    const int* wg = wq + (size_t)e * H_ * TWOI_ + c0 + bc;
    const int* wu = wg + I_;
    for (int kk = 0; kk < H_; kk += 32) {
        {
            const float* xp = xrow + kk + akg * 8;
            #pragma unroll
            for (int p = 0; p < 2; ++p) {
                float4 f0 = *(const float4*)(xp + p * 8);
                float4 f1 = *(const float4*)(xp + p * 8 + 4);
                bf16x8 v;
                v[0] = f2bf(f0.x); v[1] = f2bf(f0.y); v[2] = f2bf(f0.z); v[3] = f2bf(f0.w);
                v[4] = f2bf(f1.x); v[5] = f2bf(f1.y); v[6] = f2bf(f1.z); v[7] = f2bf(f1.w);
                *(bf16x8*)&As[akg + p][ar][0] = v;
            }
        }
        {
            const int* wpg = wg + (size_t)(kk + bkg * 8) * TWOI_;
            const int* wpu = wu + (size_t)(kk + bkg * 8) * TWOI_;
            bf16x8 vg, vu;
            #pragma unroll
            for (int j = 0; j < 8; ++j) {
                vg[j] = f2bf((float)wpg[(size_t)j * TWOI_] - 128.f);
                vu[j] = f2bf((float)wpu[(size_t)j * TWOI_] - 128.f);
            }
            *(bf16x8*)&Bg[bkg][bc][0] = vg;
            *(bf16x8*)&Bu[bkg][bc][0] = vu;
        }
        __syncthreads();
        bf16x8 a[4], bg[2], bu[2];
        #pragma unroll
        for (int rf = 0; rf < 4; ++rf) a[rf] = *(const bf16x8*)&As[kg][wrow + rf * 16 + fr][0];
        #pragma unroll
        for (int cf = 0; cf < 2; ++cf) {
            bg[cf] = *(const bf16x8*)&Bg[kg][wcc + cf * 16 + fr][0];
            bu[cf] = *(const bf16x8*)&Bu[kg][wcc + cf * 16 + fr][0];
        }
        #pragma unroll
        for (int rf = 0; rf < 4; ++rf)
            #pragma unroll
            for (int cf = 0; cf < 2; ++cf) {
                accg[rf][cf] = __builtin_amdgcn_mfma_f32_16x16x32_bf16(a[rf], bg[cf], accg[rf][cf], 0, 0, 0);
                accu[rf][cf] = __builtin_amdgcn_mfma_f32_16x16x32_bf16(a[rf], bu[cf], accu[rf][cf], 0, 0, 0);
            }
        __syncthreads();
    }
    const int q4 = lane >> 4;
    #pragma unroll
    for (int cf = 0; cf < 2; ++cf) {
        int col = c0 + wcc + cf * 16 + fr;
        float gs = scale[e * TWOI_ + col];
        float us = scale[e * TWOI_ + I_ + col];
        #pragma unroll
        for (int rf = 0; rf < 4; ++rf) {
            #pragma unroll
            for (int j = 0; j < 4; ++j) {
                int row = wrow + rf * 16 + q4 * 4 + j;
                if (row0 + row < cn) {
                    float gv = accg[rf][cf][j] * gs;
                    float uv = accu[rf][cf][j] * us;
                    float s = 1.f / (1.f + __expf(-gv));
                    h_ws[(size_t)(base + row0 + row) * I_ + col] = f2bf(gv * s * uv);
                }
            }
        }
    }
}

__global__ __launch_bounds__(256) void gemm2_kernel(
    const short* __restrict__ h_ws, const int* __restrict__ wq,
    const float* __restrict__ dscale,
    const int* __restrict__ cnt, const int* __restrict__ off,
    const int* __restrict__ toks, const float* __restrict__ wts,
    float* __restrict__ out) {
    int e = blockIdx.z;
    int cn = cnt[e];
    int row0 = blockIdx.y * 128;
    if (row0 >= cn) return;
    int base = off[e];
    int c0 = blockIdx.x * 128;
    __shared__ __align__(16) short As[4][128][8];
    __shared__ __align__(16) short Bs[4][128][8];
    __shared__ int stok[128];
    __shared__ float swt[128];
    int tid = threadIdx.x;
    if (tid < 128) {
        int r = row0 + tid;
        int idx = base + (r < cn ? r : 0);
        stok[tid] = toks[idx];
        swt[tid] = (r < cn) ? wts[idx] : 0.f;
    }
    __syncthreads();
    const int lane = tid & 63;
    const int wid = tid >> 6;
    const int wrow = (wid >> 1) * 64;
    const int wcc = (wid & 1) * 64;
    const int fr = lane & 15;
    const int kg = lane >> 4;
    f32x4 acc[4][4];
    #pragma unroll
    for (int i = 0; i < 4; ++i)
        #pragma unroll
        for (int j = 0; j < 4; ++j) acc[i][j] = f32x4{0.f, 0.f, 0.f, 0.f};
    const int ar = tid & 127;
    const int akg = (tid >> 7) * 2;
    const int bc = tid & 127;
    const int bkg2 = (tid >> 7) * 2;
    const short* hrow = h_ws + (size_t)(base + ((row0 + ar) < cn ? row0 + ar : 0)) * I_;
    const int* wcol = wq + (size_t)e * I_ * H_ + c0 + bc;
    for (int kk = 0; kk < I_; kk += 32) {
        #pragma unroll
        for (int p = 0; p < 2; ++p) {
            *(bf16x8*)&As[akg + p][ar][0] = *(const bf16x8*)(hrow + kk + (akg + p) * 8);
        }
        #pragma unroll
        for (int p = 0; p < 2; ++p) {
            const int* wp = wcol + (size_t)(kk + (bkg2 + p) * 8) * H_;
            bf16x8 v;
            #pragma unroll
            for (int j = 0; j < 8; ++j) v[j] = f2bf((float)wp[(size_t)j * H_] - 128.f);
            *(bf16x8*)&Bs[bkg2 + p][bc][0] = v;
        }
        __syncthreads();
        bf16x8 a[4], b[4];
        #pragma unroll
        for (int rf = 0; rf < 4; ++rf) a[rf] = *(const bf16x8*)&As[kg][wrow + rf * 16 + fr][0];
        #pragma unroll
        for (int cf = 0; cf < 4; ++cf) b[cf] = *(const bf16x8*)&Bs[kg][wcc + cf * 16 + fr][0];
        #pragma unroll
        for (int rf = 0; rf < 4; ++rf)
            #pragma unroll
            for (int cf = 0; cf < 4; ++cf)
                acc[rf][cf] = __builtin_amdgcn_mfma_f32_16x16x32_bf16(a[rf], b[cf], acc[rf][cf], 0, 0, 0);
        __syncthreads();
    }
    const int q4 = lane >> 4;
    #pragma unroll
    for (int cf = 0; cf < 4; ++cf) {
        int col = c0 + wcc + cf * 16 + fr;
        float ds = dscale[e * H_ + col];
        #pragma unroll
        for (int rf = 0; rf < 4; ++rf) {
            #pragma unroll
            for (int j = 0; j < 4; ++j) {
                int row = wrow + rf * 16 + q4 * 4 + j;
                if (row0 + row < cn) {
                    float v = acc[rf][cf][j] * ds * swt[row];
                    atomicAdd(&out[(size_t)stok[row] * H_ + col], v);
                }
            }
        }
    }
}

extern "C" void kernel_launch(void* const* d_in, const int* in_sizes, int n_in,
                              void* d_out, int out_size, void* d_ws, size_t ws_size,
                              hipStream_t stream) {
    const float* x     = (const float*)d_in[0];
    const float* aff   = (const float*)d_in[1];
    const int*   guq   = (const int*)d_in[2];
    const float* gus   = (const float*)d_in[3];
    const int*   dwq   = (const int*)d_in[4];
    const float* dsc   = (const float*)d_in[5];
    const int*   eidx  = (const int*)d_in[6];
    float* out = (float*)d_out;

    char* ws = (char*)d_ws;
    int* cnt = (int*)ws;
    int* off = cnt + 8;
    int* toks = (int*)(ws + 64);
    float* wts = (float*)(ws + 64 + NSLOT_ * 4);

    const size_t off_h  = (size_t)1 << 20;
    const size_t sz_h   = (size_t)NSLOT_ * I_ * 2;
    const size_t off_xb = off_h + sz_h;
    const size_t sz_xb  = (size_t)T_ * H_ * 2;
    const size_t off_gu = off_xb + sz_xb;
    const size_t sz_gu  = (size_t)E_ * 512 * TWOI_ * 8 * 2;
    const size_t off_dn = off_gu + sz_gu;
    const size_t sz_dn  = (size_t)E_ * 224 * H_ * 8 * 2;
    const size_t NEED   = off_dn + sz_dn;   // ~416 MB

    short* h_ws = (short*)(ws + off_h);

    hipMemsetAsync(d_out, 0, (size_t)out_size * sizeof(float), stream);
    route_kernel<<<1, 1024, 0, stream>>>(eidx, aff, cnt, off, toks, wts);

    if (ws_size >= NEED) {
        short* xb   = (short*)(ws + off_xb);
        short* wgur = (short*)(ws + off_gu);
        short* wdr  = (short*)(ws + off_dn);

        xconv_kernel<<<(T_ * H_) / (256 * 8), 256, 0, stream>>>(x, xb);
        dim3 rg1(TWOI_ / 256, 512, E_);
        repack_gu_kernel<<<rg1, 256, 0, stream>>>(guq, wgur);
        dim3 rg2(H_ / 256, 224, E_);
        repack_dn_kernel<<<rg2, 256, 0, stream>>>(dwq, wdr);

        gemm1x9_kernel<<<(TWOI_ / 256) * (NSLOT_ / 256) * E_, 512, 0, stream>>>(
            xb, wgur, gus, cnt, off, toks, h_ws);
        gemm2x9_kernel<<<(H_ / 256) * (NSLOT_ / 256) * E_, 512, 0, stream>>>(
            h_ws, wdr, dsc, cnt, off, toks, wts, out);
    } else {
        dim3 g1(I_ / 64, NSLOT_ / 128, E_);
        gemm1_kernel<<<g1, 256, 0, stream>>>(x, guq, gus, cnt, off, toks, h_ws);
        dim3 g2(H_ / 128, NSLOT_ / 128, E_);
        gemm2_kernel<<<g2, 256, 0, stream>>>(h_ws, dwq, dsc, cnt, off, toks, wts, out);
    }
}

// Round 8
// 1102.099 us; speedup vs baseline: 1.2263x; 1.2263x over previous
//
#include <hip/hip_runtime.h>
#include <hip/hip_bf16.h>
#include <stdint.h>

#define E_ 8
#define H_ 4096
#define I_ 1792
#define TWOI_ 3584
#define T_ 4096
#define NSLOT_ 8192
#define NS1_ 128   /* H_/32 k-slices */
#define NS2_ 56    /* I_/32 k-slices */
#define XGBLK_ 1048576   /* shorts per xg slot-block: 128*4*256*8 */
#define HPBLK_ 458752    /* shorts per h_pk slot-block: 56*4*256*8 */

typedef __attribute__((ext_vector_type(4))) float f32x4;
typedef __attribute__((ext_vector_type(8))) short bf16x8;

static __device__ __forceinline__ short f2bf(float f) {
    unsigned u = __builtin_bit_cast(unsigned, f);
    u += 0x7FFF + ((u >> 16) & 1);   // round-to-nearest-even
    return (short)(u >> 16);
}

static __device__ __forceinline__ void gld16(const void* g, void* l) {
    __builtin_amdgcn_global_load_lds(
        (const __attribute__((address_space(1))) void*)g,
        (__attribute__((address_space(3))) void*)l, 16, 0, 0);
}

#define VMW_(n) asm volatile("s_waitcnt vmcnt(" #n ")" ::: "memory")
#define VMW(n) VMW_(n)

// ---------------- routing ----------------
__global__ void route_kernel(const int* __restrict__ eidx,
                             const float* __restrict__ aff,
                             int* __restrict__ cnt, int* __restrict__ off,
                             int* __restrict__ toks, float* __restrict__ wts) {
    __shared__ int scnt[E_];
    __shared__ int soff[E_];
    int tid = threadIdx.x;
    if (tid < E_) scnt[tid] = 0;
    __syncthreads();
    for (int s = tid; s < NSLOT_; s += blockDim.x) {
        atomicAdd(&scnt[eidx[s]], 1);
    }
    __syncthreads();
    if (tid == 0) {
        int acc = 0;
        for (int e = 0; e < E_; ++e) {
            int c = scnt[e];
            cnt[e] = c; off[e] = acc; soff[e] = acc;
            acc += c;
        }
    }
    __syncthreads();
    if (tid < E_) scnt[tid] = soff[tid];
    __syncthreads();
    for (int s = tid; s < NSLOT_; s += blockDim.x) {
        int t = s >> 1;
        int e0 = eidx[t * 2], e1 = eidx[t * 2 + 1];
        float a0 = aff[t * E_ + e0], a1 = aff[t * E_ + e1];
        int k = s & 1;
        int e = k ? e1 : e0;
        float w = (k ? a1 : a0) / (a0 + a1);
        int pos = atomicAdd(&scnt[e], 1);
        toks[pos] = t;
        wts[pos] = w;
    }
}

// ---------------- gather x -> k-packet bf16 xg[blk][128][4][256][8] ----------------
// reads: each thread streams 8KB contiguous of one token row; writes coalesced.
__global__ __launch_bounds__(256) void gather_x_kernel(const float* __restrict__ x,
                                                       const int* __restrict__ toks,
                                                       short* __restrict__ xg) {
    int blk = blockIdx.x >> 3;        // 0..31
    int sc = blockIdx.x & 7;          // slice chunk (16 slices)
    int row = threadIdx.x;            // 0..255
    int g = blk * 256 + row;
    const float* src = x + (size_t)toks[g] * H_ + sc * 512;
    short* dstbase = xg + (size_t)blk * XGBLK_ + (size_t)row * 8;
    for (int s = 0; s < 16; ++s) {
        int slice = sc * 16 + s;
        #pragma unroll
        for (int kg = 0; kg < 4; ++kg) {
            float4 f0 = *(const float4*)(src + s * 32 + kg * 8);
            float4 f1 = *(const float4*)(src + s * 32 + kg * 8 + 4);
            bf16x8 v;
            v[0] = f2bf(f0.x); v[1] = f2bf(f0.y); v[2] = f2bf(f0.z); v[3] = f2bf(f0.w);
            v[4] = f2bf(f1.x); v[5] = f2bf(f1.y); v[6] = f2bf(f1.z); v[7] = f2bf(f1.w);
            *(bf16x8*)(dstbase + (size_t)(slice * 4 + kg) * 2048) = v;
        }
    }
}

// ---------------- coalesced weight repacks (LDS transpose) ----------------
// gu: out[e][y=k/8][rcol 3584][8], rcol interleaved gate/up at 16-granularity.
__global__ __launch_bounds__(256) void repack_gu_kernel(const int* __restrict__ wq,
                                                        short* __restrict__ out) {
    __shared__ short sm[64][33];      // [krow][col32] +pad
    int e = blockIdx.z;
    int by = blockIdx.y;              // 0..63  (64 k-rows each)
    int bx = blockIdx.x;              // 0..111 (32 repacked cols each)
    int tid = threadIdx.x;
    {   // phase 1: 64 rows x 32 cols, each thread 8 contiguous int32
        int rw = tid >> 2;            // 0..63
        int q = tid & 3;              // col-octet
        int ocol = (q < 2) ? (bx * 16 + q * 8) : (I_ + bx * 16 + (q - 2) * 8);
        const int* src = wq + ((size_t)e * H_ + by * 64 + rw) * TWOI_ + ocol;
        #pragma unroll
        for (int i = 0; i < 8; ++i)
            sm[rw][q * 8 + i] = f2bf((float)(src[i] - 128));
    }
    __syncthreads();
    {   // phase 2: each thread writes one (y, col) 16B packet
        int yl = tid >> 5;            // 0..7
        int c = tid & 31;
        bf16x8 v;
        #pragma unroll
        for (int i = 0; i < 8; ++i) v[i] = sm[yl * 8 + i][c];
        *(bf16x8*)(out + (((size_t)e * 512 + by * 8 + yl) * TWOI_ + bx * 32 + c) * 8) = v;
    }
}

__global__ __launch_bounds__(256) void repack_dn_kernel(const int* __restrict__ wq,
                                                        short* __restrict__ out) {
    __shared__ short sm[64][33];
    int e = blockIdx.z;
    int by = blockIdx.y;              // 0..27
    int bx = blockIdx.x;              // 0..127
    int tid = threadIdx.x;
    {
        int rw = tid >> 2;
        int q = tid & 3;
        const int* src = wq + ((size_t)e * I_ + by * 64 + rw) * H_ + bx * 32 + q * 8;
        #pragma unroll
        for (int i = 0; i < 8; ++i)
            sm[rw][q * 8 + i] = f2bf((float)(src[i] - 128));
    }
    __syncthreads();
    {
        int yl = tid >> 5;
        int c = tid & 31;
        bf16x8 v;
        #pragma unroll
        for (int i = 0; i < 8; ++i) v[i] = sm[yl * 8 + i][c];
        *(bf16x8*)(out + (((size_t)e * 224 + by * 8 + yl) * H_ + bx * 32 + c) * 8) = v;
    }
}

// ==================== GEMM1 ring-4 depth-3, all-coalesced: 256x256 ====================
__global__ __launch_bounds__(512, 1) void gemm1r_kernel(
    const short* __restrict__ xg,       // k-packet A
    const short* __restrict__ wgu,      // k-packet B (interleaved g/u)
    const float* __restrict__ scale,    // [E,2I]
    const int* __restrict__ cnt, const int* __restrict__ off,
    short* __restrict__ h_pk) {         // k-packet h
    const int id = blockIdx.x;
    const int e = id & 7;
    const int j = id >> 3;
    const int bx = j >> 5;              // 0..13
    const int by = j & 31;
    int cn = cnt[e];
    int row0 = by * 256;
    if (row0 >= cn) return;
    int base = off[e];

    __shared__ __align__(16) short SM[65536];   // A: [0,32768) B: [32768,65536)

    int tid = threadIdx.x;
    const int lane = tid & 63;
    const int wid = tid >> 6;
    const int wr128 = (wid >> 2) * 128;
    const int wc64 = (wid & 3) * 64;
    const int fr = lane & 15;
    const int kq = lane >> 4;

    const int srow = tid & 255;
    const int kgo2 = (tid >> 8) * 2;    // 0 or 2

    int ga = row0 + srow; if (ga >= cn) ga = cn - 1;
    ga += base;
    const size_t aoff = (size_t)(ga >> 8) * XGBLK_ + (size_t)(ga & 255) * 8;
    const size_t bstride = (size_t)TWOI_ * 8;
    const short* bsrc = wgu + (size_t)e * 512 * bstride + (size_t)(bx * 256 + srow) * 8;

    bf16x8 av[8], bv[4];
    f32x4 acc[8][4];
    #pragma unroll
    for (int i = 0; i < 8; ++i)
        #pragma unroll
        for (int jj = 0; jj < 4; ++jj) acc[i][jj] = f32x4{0.f, 0.f, 0.f, 0.f};

#define G1_STG(q, slot) do {                                              \
        _Pragma("unroll")                                                 \
        for (int p_ = 0; p_ < 2; ++p_)                                    \
            gld16(xg + aoff + (size_t)((q) * 4 + kgo2 + p_) * 2048,       \
                  &SM[(((slot) * 4 + kgo2 + p_) * 256 + srow) * 8]);      \
        _Pragma("unroll")                                                 \
        for (int p_ = 0; p_ < 2; ++p_)                                    \
            gld16(bsrc + (size_t)((q) * 4 + kgo2 + p_) * bstride,         \
                  &SM[32768 + (((slot) * 4 + kgo2 + p_) * 256 + srow) * 8]); \
    } while (0)
#define G1_RD(ss) do {                                                    \
        _Pragma("unroll") for (int i_ = 0; i_ < 8; ++i_)                  \
            av[i_] = *(const bf16x8*)&SM[(((ss) * 4 + kq) * 256 + wr128 + i_ * 16 + fr) * 8]; \
        _Pragma("unroll") for (int j_ = 0; j_ < 4; ++j_)                  \
            bv[j_] = *(const bf16x8*)&SM[32768 + (((ss) * 4 + kq) * 256 + wc64 + j_ * 16 + fr) * 8]; \
    } while (0)
#define G1_MM() do {                                                      \
        __builtin_amdgcn_s_setprio(1);                                    \
        _Pragma("unroll") for (int i_ = 0; i_ < 8; ++i_)                  \
        _Pragma("unroll") for (int j_ = 0; j_ < 4; ++j_)                  \
            acc[i_][j_] = __builtin_amdgcn_mfma_f32_16x16x32_bf16(av[i_], bv[j_], acc[i_][j_], 0, 0, 0); \
        __builtin_amdgcn_s_setprio(0);                                    \
    } while (0)
#define G1_PH(ss, q, qs, V, DOSTG) do {                                   \
        VMW(V);                                                           \
        __builtin_amdgcn_s_barrier();                                     \
        __builtin_amdgcn_sched_barrier(0);                                \
        if (DOSTG) G1_STG(q, qs);                                         \
        G1_RD(ss);                                                        \
        G1_MM();                                                          \
    } while (0)

    G1_STG(0, 0); G1_STG(1, 1); G1_STG(2, 2);
    for (int sb = 0; sb < NS1_ - 4; sb += 4) {
        G1_PH(0, sb + 3, 3, 8, 1);
        G1_PH(1, sb + 4, 0, 8, 1);
        G1_PH(2, sb + 5, 1, 8, 1);
        G1_PH(3, sb + 6, 2, 8, 1);
    }
    G1_PH(0, NS1_ - 1, 3, 8, 1);
    G1_PH(1, 0, 0, 8, 0);
    G1_PH(2, 0, 0, 4, 0);
    G1_PH(3, 0, 0, 0, 0);
#undef G1_STG
#undef G1_RD
#undef G1_MM
#undef G1_PH

    // ---- epilogue: silu(g)*u -> LDS transpose -> k-packet h_pk ----
    __syncthreads();                 // all waves done with staging LDS
    const int q4 = lane >> 4;
    #pragma unroll
    for (int cfp = 0; cfp < 2; ++cfp) {
        int ml = (wid & 3) * 2 + cfp;           // local 16-col block 0..7
        int hcol = (bx * 8 + ml) * 16 + fr;     // global h col
        float gs = scale[e * TWOI_ + hcol];
        float us = scale[e * TWOI_ + I_ + hcol];
        int cl = ml * 16 + fr;                  // local col 0..127
        #pragma unroll
        for (int rf = 0; rf < 8; ++rf) {
            #pragma unroll
            for (int jj = 0; jj < 4; ++jj) {
                int row = wr128 + rf * 16 + q4 * 4 + jj;
                float gv = acc[rf][cfp * 2][jj] * gs;
                float uv = acc[rf][cfp * 2 + 1][jj] * us;
                float s = 1.f / (1.f + __expf(-gv));
                SM[row * 136 + cl] = f2bf(gv * s * uv);
            }
        }
    }
    __syncthreads();
    #pragma unroll
    for (int v = 0; v < 8; ++v) {
        int l = tid & 63;
        int w = tid >> 6;
        int o = w * 2 + (v & 1);                // col octet 0..15
        int rloc = (v >> 1) * 64 + l;           // 0..255
        if (rloc < cn - row0) {
            int g = base + row0 + rloc;
            bf16x8 hv = *(const bf16x8*)&SM[rloc * 136 + o * 8];
            size_t dst = (size_t)(g >> 8) * HPBLK_
                       + (size_t)((bx * 4 + (o >> 2)) * 4 + (o & 3)) * 2048
                       + (size_t)(g & 255) * 8;
            *(bf16x8*)(h_pk + dst) = hv;
        }
    }
}

// ==================== GEMM2 ring-4 depth-3, all-coalesced: 256x256 ====================
__global__ __launch_bounds__(512, 1) void gemm2r_kernel(
    const short* __restrict__ h_pk,     // k-packet A
    const short* __restrict__ wd,       // k-packet B
    const float* __restrict__ dscale,   // [E,H]
    const int* __restrict__ cnt, const int* __restrict__ off,
    const int* __restrict__ toks, const float* __restrict__ wts,
    float* __restrict__ out) {          // [T,H]
    const int id = blockIdx.x;
    const int e = id & 7;
    const int j = id >> 3;
    const int bx = j >> 5;              // 0..15
    const int by = j & 31;
    int cn = cnt[e];
    int row0 = by * 256;
    if (row0 >= cn) return;
    int base = off[e];

    __shared__ __align__(16) short SM[65536];
    __shared__ int stok[256];
    __shared__ float swt[256];

    int tid = threadIdx.x;
    if (tid < 256) {
        int r = row0 + tid;
        int idx = base + (r < cn ? r : cn - 1);
        stok[tid] = toks[idx];
        swt[tid] = (r < cn) ? wts[idx] : 0.f;
    }
    __syncthreads();

    const int lane = tid & 63;
    const int wid = tid >> 6;
    const int wr128 = (wid >> 2) * 128;
    const int wc64 = (wid & 3) * 64;
    const int fr = lane & 15;
    const int kq = lane >> 4;

    const int srow = tid & 255;
    const int kgo2 = (tid >> 8) * 2;

    int ga = row0 + srow; if (ga >= cn) ga = cn - 1;
    ga += base;
    const size_t aoff = (size_t)(ga >> 8) * HPBLK_ + (size_t)(ga & 255) * 8;
    const size_t bstride = (size_t)H_ * 8;
    const short* bsrc = wd + (size_t)e * 224 * bstride + (size_t)(bx * 256 + srow) * 8;

    bf16x8 av[8], bv[4];
    f32x4 acc[8][4];
    #pragma unroll
    for (int i = 0; i < 8; ++i)
        #pragma unroll
        for (int jj = 0; jj < 4; ++jj) acc[i][jj] = f32x4{0.f, 0.f, 0.f, 0.f};

#define G2_STG(q, slot) do {                                              \
        _Pragma("unroll")                                                 \
        for (int p_ = 0; p_ < 2; ++p_)                                    \
            gld16(h_pk + aoff + (size_t)((q) * 4 + kgo2 + p_) * 2048,     \
                  &SM[(((slot) * 4 + kgo2 + p_) * 256 + srow) * 8]);      \
        _Pragma("unroll")                                                 \
        for (int p_ = 0; p_ < 2; ++p_)                                    \
            gld16(bsrc + (size_t)((q) * 4 + kgo2 + p_) * bstride,         \
                  &SM[32768 + (((slot) * 4 + kgo2 + p_) * 256 + srow) * 8]); \
    } while (0)
#define G2_RD(ss) do {                                                    \
        _Pragma("unroll") for (int i_ = 0; i_ < 8; ++i_)                  \
            av[i_] = *(const bf16x8*)&SM[(((ss) * 4 + kq) * 256 + wr128 + i_ * 16 + fr) * 8]; \
        _Pragma("unroll") for (int j_ = 0; j_ < 4; ++j_)                  \
            bv[j_] = *(const bf16x8*)&SM[32768 + (((ss) * 4 + kq) * 256 + wc64 + j_ * 16 + fr) * 8]; \
    } while (0)
#define G2_MM() do {                                                      \
        __builtin_amdgcn_s_setprio(1);                                    \
        _Pragma("unroll") for (int i_ = 0; i_ < 8; ++i_)                  \
        _Pragma("unroll") for (int j_ = 0; j_ < 4; ++j_)                  \
            acc[i_][j_] = __builtin_amdgcn_mfma_f32_16x16x32_bf16(av[i_], bv[j_], acc[i_][j_], 0, 0, 0); \
        __builtin_amdgcn_s_setprio(0);                                    \
    } while (0)
#define G2_PH(ss, q, qs, V, DOSTG) do {                                   \
        VMW(V);                                                           \
        __builtin_amdgcn_s_barrier();                                     \
        __builtin_amdgcn_sched_barrier(0);                                \
        if (DOSTG) G2_STG(q, qs);                                         \
        G2_RD(ss);                                                        \
        G2_MM();                                                          \
    } while (0)

    G2_STG(0, 0); G2_STG(1, 1); G2_STG(2, 2);
    for (int sb = 0; sb < NS2_ - 4; sb += 4) {
        G2_PH(0, sb + 3, 3, 8, 1);
        G2_PH(1, sb + 4, 0, 8, 1);
        G2_PH(2, sb + 5, 1, 8, 1);
        G2_PH(3, sb + 6, 2, 8, 1);
    }
    G2_PH(0, NS2_ - 1, 3, 8, 1);
    G2_PH(1, 0, 0, 8, 0);
    G2_PH(2, 0, 0, 4, 0);
    G2_PH(3, 0, 0, 0, 0);
#undef G2_STG
#undef G2_RD
#undef G2_MM
#undef G2_PH

    const int q4 = lane >> 4;
    #pragma unroll
    for (int cf = 0; cf < 4; ++cf) {
        int col = bx * 256 + wc64 + cf * 16 + fr;
        float ds = dscale[e * H_ + col];
        #pragma unroll
        for (int rf = 0; rf < 8; ++rf) {
            #pragma unroll
            for (int jj = 0; jj < 4; ++jj) {
                int row = wr128 + rf * 16 + q4 * 4 + jj;
                if (row0 + row < cn) {
                    float v = acc[rf][cf][jj] * ds * swt[row];
                    atomicAdd(&out[(size_t)stok[row] * H_ + col], v);
                }
            }
        }
    }
}

// ================= fallback path (fused int32 dequant, known-good) =================
__global__ __launch_bounds__(256) void gemm1_kernel(
    const float* __restrict__ x, const int* __restrict__ wq,
    const float* __restrict__ scale,
    const int* __restrict__ cnt, const int* __restrict__ off,
    const int* __restrict__ toks, short* __restrict__ h_ws) {
    int e = blockIdx.z;
    int cn = cnt[e];
    int row0 = blockIdx.y * 128;
    if (row0 >= cn) return;
    int base = off[e];
    int c0 = blockIdx.x * 64;
    __shared__ __align__(16) short As[4][128][8];
    __shared__ __align__(16) short Bg[4][64][8];
    __shared__ __align__(16) short Bu[4][64][8];
    __shared__ int stok[128];
    int tid = threadIdx.x;
    if (tid < 128) {
        int r = row0 + tid;
        stok[tid] = toks[base + (r < cn ? r : 0)];
    }
    __syncthreads();
    const int lane = tid & 63;
    const int wid = tid >> 6;
    const int wrow = (wid >> 1) * 64;
    const int wcc = (wid & 1) * 32;
    const int fr = lane & 15;
    const int kg = lane >> 4;
    f32x4 accg[4][2], accu[4][2];
    #pragma unroll
    for (int i = 0; i < 4; ++i)
        #pragma unroll
        for (int j = 0; j < 2; ++j) {
            accg[i][j] = f32x4{0.f, 0.f, 0.f, 0.f};
            accu[i][j] = f32x4{0.f, 0.f, 0.f, 0.f};
        }
    const int ar = tid & 127;
    const int akg = (tid >> 7) * 2;
    const int bc = tid & 63;
    const int bkg = (tid >> 6) & 3;
    const float* xrow = x + (size_t)stok[ar] * H_;
    const int* wg = wq + (size_t)e * H_ * TWOI_ + c0 + bc;
    const int* wu = wg + I_;
    for (int kk = 0; kk < H_; kk += 32) {
        {
            const float* xp = xrow + kk + akg * 8;
            #pragma unroll
            for (int p = 0; p < 2; ++p) {
                float4 f0 = *(const float4*)(xp + p * 8);
                float4 f1 = *(const float4*)(xp + p * 8 + 4);
                bf16x8 v;
                v[0] = f2bf(f0.x); v[1] = f2bf(f0.y); v[2] = f2bf(f0.z); v[3] = f2bf(f0.w);
                v[4] = f2bf(f1.x); v[5] = f2bf(f1.y); v[6] = f2bf(f1.z); v[7] = f2bf(f1.w);
                *(bf16x8*)&As[akg + p][ar][0] = v;
            }
        }
        {
            const int* wpg = wg + (size_t)(kk + bkg * 8) * TWOI_;
            const int* wpu = wu + (size_t)(kk + bkg * 8) * TWOI_;
            bf16x8 vg, vu;
            #pragma unroll
            for (int j = 0; j < 8; ++j) {
                vg[j] = f2bf((float)wpg[(size_t)j * TWOI_] - 128.f);
                vu[j] = f2bf((float)wpu[(size_t)j * TWOI_] - 128.f);
            }
            *(bf16x8*)&Bg[bkg][bc][0] = vg;
            *(bf16x8*)&Bu[bkg][bc][0] = vu;
        }
        __syncthreads();
        bf16x8 a[4], bg[2], bu[2];
        #pragma unroll
        for (int rf = 0; rf < 4; ++rf) a[rf] = *(const bf16x8*)&As[kg][wrow + rf * 16 + fr][0];
        #pragma unroll
        for (int cf = 0; cf < 2; ++cf) {
            bg[cf] = *(const bf16x8*)&Bg[kg][wcc + cf * 16 + fr][0];
            bu[cf] = *(const bf16x8*)&Bu[kg][wcc + cf * 16 + fr][0];
        }
        #pragma unroll
        for (int rf = 0; rf < 4; ++rf)
            #pragma unroll
            for (int cf = 0; cf < 2; ++cf) {
                accg[rf][cf] = __builtin_amdgcn_mfma_f32_16x16x32_bf16(a[rf], bg[cf], accg[rf][cf], 0, 0, 0);
                accu[rf][cf] = __builtin_amdgcn_mfma_f32_16x16x32_bf16(a[rf], bu[cf], accu[rf][cf], 0, 0, 0);
            }
        __syncthreads();
    }
    const int q4 = lane >> 4;
    #pragma unroll
    for (int cf = 0; cf < 2; ++cf) {
        int col = c0 + wcc + cf * 16 + fr;
        float gs = scale[e * TWOI_ + col];
        float us = scale[e * TWOI_ + I_ + col];
        #pragma unroll
        for (int rf = 0; rf < 4; ++rf) {
            #pragma unroll
            for (int j = 0; j < 4; ++j) {
                int row = wrow + rf * 16 + q4 * 4 + j;
                if (row0 + row < cn) {
                    float gv = accg[rf][cf][j] * gs;
                    float uv = accu[rf][cf][j] * us;
                    float s = 1.f / (1.f + __expf(-gv));
                    h_ws[(size_t)(base + row0 + row) * I_ + col] = f2bf(gv * s * uv);
                }
            }
        }
    }
}

__global__ __launch_bounds__(256) void gemm2_kernel(
    const short* __restrict__ h_ws, const int* __restrict__ wq,
    const float* __restrict__ dscale,
    const int* __restrict__ cnt, const int* __restrict__ off,
    const int* __restrict__ toks, const float* __restrict__ wts,
    float* __restrict__ out) {
    int e = blockIdx.z;
    int cn = cnt[e];
    int row0 = blockIdx.y * 128;
    if (row0 >= cn) return;
    int base = off[e];
    int c0 = blockIdx.x * 128;
    __shared__ __align__(16) short As[4][128][8];
    __shared__ __align__(16) short Bs[4][128][8];
    __shared__ int stok[128];
    __shared__ float swt[128];
    int tid = threadIdx.x;
    if (tid < 128) {
        int r = row0 + tid;
        int idx = base + (r < cn ? r : 0);
        stok[tid] = toks[idx];
        swt[tid] = (r < cn) ? wts[idx] : 0.f;
    }
    __syncthreads();
    const int lane = tid & 63;
    const int wid = tid >> 6;
    const int wrow = (wid >> 1) * 64;
    const int wcc = (wid & 1) * 64;
    const int fr = lane & 15;
    const int kg = lane >> 4;
    f32x4 acc[4][4];
    #pragma unroll
    for (int i = 0; i < 4; ++i)
        #pragma unroll
        for (int j = 0; j < 4; ++j) acc[i][j] = f32x4{0.f, 0.f, 0.f, 0.f};
    const int ar = tid & 127;
    const int akg = (tid >> 7) * 2;
    const int bc = tid & 127;
    const int bkg2 = (tid >> 7) * 2;
    const short* hrow = h_ws + (size_t)(base + ((row0 + ar) < cn ? row0 + ar : 0)) * I_;
    const int* wcol = wq + (size_t)e * I_ * H_ + c0 + bc;
    for (int kk = 0; kk < I_; kk += 32) {
        #pragma unroll
        for (int p = 0; p < 2; ++p) {
            *(bf16x8*)&As[akg + p][ar][0] = *(const bf16x8*)(hrow + kk + (akg + p) * 8);
        }
        #pragma unroll
        for (int p = 0; p < 2; ++p) {
            const int* wp = wcol + (size_t)(kk + (bkg2 + p) * 8) * H_;
            bf16x8 v;
            #pragma unroll
            for (int j = 0; j < 8; ++j) v[j] = f2bf((float)wp[(size_t)j * H_] - 128.f);
            *(bf16x8*)&Bs[bkg2 + p][bc][0] = v;
        }
        __syncthreads();
        bf16x8 a[4], b[4];
        #pragma unroll
        for (int rf = 0; rf < 4; ++rf) a[rf] = *(const bf16x8*)&As[kg][wrow + rf * 16 + fr][0];
        #pragma unroll
        for (int cf = 0; cf < 4; ++cf) b[cf] = *(const bf16x8*)&Bs[kg][wcc + cf * 16 + fr][0];
        #pragma unroll
        for (int rf = 0; rf < 4; ++rf)
            #pragma unroll
            for (int cf = 0; cf < 4; ++cf)
                acc[rf][cf] = __builtin_amdgcn_mfma_f32_16x16x32_bf16(a[rf], b[cf], acc[rf][cf], 0, 0, 0);
        __syncthreads();
    }
    const int q4 = lane >> 4;
    #pragma unroll
    for (int cf = 0; cf < 4; ++cf) {
        int col = c0 + wcc + cf * 16 + fr;
        float ds = dscale[e * H_ + col];
        #pragma unroll
        for (int rf = 0; rf < 4; ++rf) {
            #pragma unroll
            for (int j = 0; j < 4; ++j) {
                int row = wrow + rf * 16 + q4 * 4 + j;
                if (row0 + row < cn) {
                    float v = acc[rf][cf][j] * ds * swt[row];
                    atomicAdd(&out[(size_t)stok[row] * H_ + col], v);
                }
            }
        }
    }
}

extern "C" void kernel_launch(void* const* d_in, const int* in_sizes, int n_in,
                              void* d_out, int out_size, void* d_ws, size_t ws_size,
                              hipStream_t stream) {
    const float* x     = (const float*)d_in[0];
    const float* aff   = (const float*)d_in[1];
    const int*   guq   = (const int*)d_in[2];
    const float* gus   = (const float*)d_in[3];
    const int*   dwq   = (const int*)d_in[4];
    const float* dsc   = (const float*)d_in[5];
    const int*   eidx  = (const int*)d_in[6];
    float* out = (float*)d_out;

    char* ws = (char*)d_ws;
    int* cnt = (int*)ws;
    int* off = cnt + 8;
    int* toks = (int*)(ws + 64);
    float* wts = (float*)(ws + 64 + NSLOT_ * 4);

    const size_t off_h  = (size_t)1 << 20;
    const size_t sz_h   = (size_t)NSLOT_ * I_ * 2;          // 29.36 MB (h_pk / h_ws)
    const size_t off_xg = off_h + sz_h;
    const size_t sz_xg  = (size_t)NSLOT_ * H_ * 2;          // 67.1 MB
    const size_t off_gu = off_xg + sz_xg;
    const size_t sz_gu  = (size_t)E_ * 512 * TWOI_ * 8 * 2; // 234.9 MB
    const size_t off_dn = off_gu + sz_gu;
    const size_t sz_dn  = (size_t)E_ * 224 * H_ * 8 * 2;    // 117.4 MB
    const size_t NEED   = off_dn + sz_dn;                   // ~450 MB

    short* h_ws = (short*)(ws + off_h);

    hipMemsetAsync(d_out, 0, (size_t)out_size * sizeof(float), stream);
    route_kernel<<<1, 1024, 0, stream>>>(eidx, aff, cnt, off, toks, wts);

    if (ws_size >= NEED) {
        short* xg   = (short*)(ws + off_xg);
        short* wgur = (short*)(ws + off_gu);
        short* wdr  = (short*)(ws + off_dn);

        gather_x_kernel<<<256, 256, 0, stream>>>(x, toks, xg);
        dim3 rg1(TWOI_ / 32, H_ / 64, E_);
        repack_gu_kernel<<<rg1, 256, 0, stream>>>(guq, wgur);
        dim3 rg2(H_ / 32, I_ / 64, E_);
        repack_dn_kernel<<<rg2, 256, 0, stream>>>(dwq, wdr);

        gemm1r_kernel<<<(TWOI_ / 256) * (NSLOT_ / 256) * E_, 512, 0, stream>>>(
            xg, wgur, gus, cnt, off, h_ws /* = h_pk */);
        gemm2r_kernel<<<(H_ / 256) * (NSLOT_ / 256) * E_, 512, 0, stream>>>(
            h_ws, wdr, dsc, cnt, off, toks, wts, out);
    } else {
        dim3 g1(I_ / 64, NSLOT_ / 128, E_);
        gemm1_kernel<<<g1, 256, 0, stream>>>(x, guq, gus, cnt, off, toks, h_ws);
        dim3 g2(H_ / 128, NSLOT_ / 128, E_);
        gemm2_kernel<<<g2, 256, 0, stream>>>(h_ws, dwq, dsc, cnt, off, toks, wts, out);
    }
}

// Round 9
// 933.979 us; speedup vs baseline: 1.4471x; 1.1800x over previous
//
#include <hip/hip_runtime.h>
#include <hip/hip_bf16.h>
#include <stdint.h>

#define E_ 8
#define H_ 4096
#define I_ 1792
#define TWOI_ 3584
#define T_ 4096
#define NSLOT_ 8192
#define NS1_ 128   /* H_/32 k-slices */
#define NS2_ 56    /* I_/32 k-slices */
#define XGBLK_ 1048576   /* shorts per xg slot-block: 128*4*256*8 */
#define HPBLK_ 458752    /* shorts per h_pk slot-block: 56*4*256*8 */

typedef __attribute__((ext_vector_type(4))) float f32x4;
typedef __attribute__((ext_vector_type(8))) short bf16x8;

static __device__ __forceinline__ short f2bf(float f) {
    unsigned u = __builtin_bit_cast(unsigned, f);
    u += 0x7FFF + ((u >> 16) & 1);   // round-to-nearest-even
    return (short)(u >> 16);
}

static __device__ __forceinline__ float bf2f(short s) {
    unsigned u = ((unsigned)(unsigned short)s) << 16;
    return __builtin_bit_cast(float, u);
}

static __device__ __forceinline__ void gld16(const void* g, void* l) {
    __builtin_amdgcn_global_load_lds(
        (const __attribute__((address_space(1))) void*)g,
        (__attribute__((address_space(3))) void*)l, 16, 0, 0);
}

#define VMW_(n) asm volatile("s_waitcnt vmcnt(" #n ")" ::: "memory")
#define VMW(n) VMW_(n)

// ---------------- routing (also builds inverse slot map) ----------------
__global__ void route_kernel(const int* __restrict__ eidx,
                             const float* __restrict__ aff,
                             int* __restrict__ cnt, int* __restrict__ off,
                             int* __restrict__ toks, float* __restrict__ wts,
                             int* __restrict__ inv) {
    __shared__ int scnt[E_];
    __shared__ int soff[E_];
    int tid = threadIdx.x;
    if (tid < E_) scnt[tid] = 0;
    __syncthreads();
    for (int s = tid; s < NSLOT_; s += blockDim.x) {
        atomicAdd(&scnt[eidx[s]], 1);
    }
    __syncthreads();
    if (tid == 0) {
        int acc = 0;
        for (int e = 0; e < E_; ++e) {
            int c = scnt[e];
            cnt[e] = c; off[e] = acc; soff[e] = acc;
            acc += c;
        }
    }
    __syncthreads();
    if (tid < E_) scnt[tid] = soff[tid];
    __syncthreads();
    for (int s = tid; s < NSLOT_; s += blockDim.x) {
        int t = s >> 1;
        int e0 = eidx[t * 2], e1 = eidx[t * 2 + 1];
        float a0 = aff[t * E_ + e0], a1 = aff[t * E_ + e1];
        int k = s & 1;
        int e = k ? e1 : e0;
        float w = (k ? a1 : a0) / (a0 + a1);
        int pos = atomicAdd(&scnt[e], 1);
        toks[pos] = t;
        wts[pos] = w;
        inv[s] = pos;
    }
}

// ---------------- gather x -> k-packet bf16 xg[blk][128][4][256][8] ----------------
__global__ __launch_bounds__(256) void gather_x_kernel(const float* __restrict__ x,
                                                       const int* __restrict__ toks,
                                                       short* __restrict__ xg) {
    int blk = blockIdx.x >> 3;        // 0..31
    int sc = blockIdx.x & 7;          // slice chunk (16 slices)
    int row = threadIdx.x;            // 0..255
    int g = blk * 256 + row;
    const float* src = x + (size_t)toks[g] * H_ + sc * 512;
    short* dstbase = xg + (size_t)blk * XGBLK_ + (size_t)row * 8;
    for (int s = 0; s < 16; ++s) {
        int slice = sc * 16 + s;
        #pragma unroll
        for (int kg = 0; kg < 4; ++kg) {
            float4 f0 = *(const float4*)(src + s * 32 + kg * 8);
            float4 f1 = *(const float4*)(src + s * 32 + kg * 8 + 4);
            bf16x8 v;
            v[0] = f2bf(f0.x); v[1] = f2bf(f0.y); v[2] = f2bf(f0.z); v[3] = f2bf(f0.w);
            v[4] = f2bf(f1.x); v[5] = f2bf(f1.y); v[6] = f2bf(f1.z); v[7] = f2bf(f1.w);
            *(bf16x8*)(dstbase + (size_t)(slice * 4 + kg) * 2048) = v;
        }
    }
}

// ---------------- coalesced weight repacks (LDS transpose) ----------------
__global__ __launch_bounds__(256) void repack_gu_kernel(const int* __restrict__ wq,
                                                        short* __restrict__ out) {
    __shared__ short sm[64][33];
    int e = blockIdx.z;
    int by = blockIdx.y;              // 0..63
    int bx = blockIdx.x;              // 0..111
    int tid = threadIdx.x;
    {
        int rw = tid >> 2;
        int q = tid & 3;
        int ocol = (q < 2) ? (bx * 16 + q * 8) : (I_ + bx * 16 + (q - 2) * 8);
        const int* src = wq + ((size_t)e * H_ + by * 64 + rw) * TWOI_ + ocol;
        #pragma unroll
        for (int i = 0; i < 8; ++i)
            sm[rw][q * 8 + i] = f2bf((float)(src[i] - 128));
    }
    __syncthreads();
    {
        int yl = tid >> 5;
        int c = tid & 31;
        bf16x8 v;
        #pragma unroll
        for (int i = 0; i < 8; ++i) v[i] = sm[yl * 8 + i][c];
        *(bf16x8*)(out + (((size_t)e * 512 + by * 8 + yl) * TWOI_ + bx * 32 + c) * 8) = v;
    }
}

__global__ __launch_bounds__(256) void repack_dn_kernel(const int* __restrict__ wq,
                                                        short* __restrict__ out) {
    __shared__ short sm[64][33];
    int e = blockIdx.z;
    int by = blockIdx.y;              // 0..27
    int bx = blockIdx.x;              // 0..127
    int tid = threadIdx.x;
    {
        int rw = tid >> 2;
        int q = tid & 3;
        const int* src = wq + ((size_t)e * I_ + by * 64 + rw) * H_ + bx * 32 + q * 8;
        #pragma unroll
        for (int i = 0; i < 8; ++i)
            sm[rw][q * 8 + i] = f2bf((float)(src[i] - 128));
    }
    __syncthreads();
    {
        int yl = tid >> 5;
        int c = tid & 31;
        bf16x8 v;
        #pragma unroll
        for (int i = 0; i < 8; ++i) v[i] = sm[yl * 8 + i][c];
        *(bf16x8*)(out + (((size_t)e * 224 + by * 8 + yl) * H_ + bx * 32 + c) * 8) = v;
    }
}

// ==================== GEMM1 ring-4 depth-3, all-coalesced: 256x256 ====================
__global__ __launch_bounds__(512, 1) void gemm1r_kernel(
    const short* __restrict__ xg,       // k-packet A
    const short* __restrict__ wgu,      // k-packet B (interleaved g/u)
    const float* __restrict__ scale,    // [E,2I]
    const int* __restrict__ cnt, const int* __restrict__ off,
    short* __restrict__ h_pk) {         // k-packet h
    const int id = blockIdx.x;
    const int e = id & 7;
    const int j = id >> 3;
    const int bx = j >> 5;              // 0..13
    const int by = j & 31;
    int cn = cnt[e];
    int row0 = by * 256;
    if (row0 >= cn) return;
    int base = off[e];

    __shared__ __align__(16) short SM[65536];   // A: [0,32768) B: [32768,65536)

    int tid = threadIdx.x;
    const int lane = tid & 63;
    const int wid = tid >> 6;
    const int wr128 = (wid >> 2) * 128;
    const int wc64 = (wid & 3) * 64;
    const int fr = lane & 15;
    const int kq = lane >> 4;

    const int srow = tid & 255;
    const int kgo2 = (tid >> 8) * 2;    // 0 or 2

    int ga = row0 + srow; if (ga >= cn) ga = cn - 1;
    ga += base;
    const size_t aoff = (size_t)(ga >> 8) * XGBLK_ + (size_t)(ga & 255) * 8;
    const size_t bstride = (size_t)TWOI_ * 8;
    const short* bsrc = wgu + (size_t)e * 512 * bstride + (size_t)(bx * 256 + srow) * 8;

    bf16x8 av[8], bv[4];
    f32x4 acc[8][4];
    #pragma unroll
    for (int i = 0; i < 8; ++i)
        #pragma unroll
        for (int jj = 0; jj < 4; ++jj) acc[i][jj] = f32x4{0.f, 0.f, 0.f, 0.f};

#define G1_STG(q, slot) do {                                              \
        _Pragma("unroll")                                                 \
        for (int p_ = 0; p_ < 2; ++p_)                                    \
            gld16(xg + aoff + (size_t)((q) * 4 + kgo2 + p_) * 2048,       \
                  &SM[(((slot) * 4 + kgo2 + p_) * 256 + srow) * 8]);      \
        _Pragma("unroll")                                                 \
        for (int p_ = 0; p_ < 2; ++p_)                                    \
            gld16(bsrc + (size_t)((q) * 4 + kgo2 + p_) * bstride,         \
                  &SM[32768 + (((slot) * 4 + kgo2 + p_) * 256 + srow) * 8]); \
    } while (0)
#define G1_RD(ss) do {                                                    \
        _Pragma("unroll") for (int i_ = 0; i_ < 8; ++i_)                  \
            av[i_] = *(const bf16x8*)&SM[(((ss) * 4 + kq) * 256 + wr128 + i_ * 16 + fr) * 8]; \
        _Pragma("unroll") for (int j_ = 0; j_ < 4; ++j_)                  \
            bv[j_] = *(const bf16x8*)&SM[32768 + (((ss) * 4 + kq) * 256 + wc64 + j_ * 16 + fr) * 8]; \
    } while (0)
#define G1_MM() do {                                                      \
        __builtin_amdgcn_s_setprio(1);                                    \
        _Pragma("unroll") for (int i_ = 0; i_ < 8; ++i_)                  \
        _Pragma("unroll") for (int j_ = 0; j_ < 4; ++j_)                  \
            acc[i_][j_] = __builtin_amdgcn_mfma_f32_16x16x32_bf16(av[i_], bv[j_], acc[i_][j_], 0, 0, 0); \
        __builtin_amdgcn_s_setprio(0);                                    \
    } while (0)
#define G1_PH(ss, q, qs, V, DOSTG) do {                                   \
        VMW(V);                                                           \
        __builtin_amdgcn_s_barrier();                                     \
        __builtin_amdgcn_sched_barrier(0);                                \
        if (DOSTG) G1_STG(q, qs);                                         \
        G1_RD(ss);                                                        \
        G1_MM();                                                          \
    } while (0)

    G1_STG(0, 0); G1_STG(1, 1); G1_STG(2, 2);
    for (int sb = 0; sb < NS1_ - 4; sb += 4) {
        G1_PH(0, sb + 3, 3, 8, 1);
        G1_PH(1, sb + 4, 0, 8, 1);
        G1_PH(2, sb + 5, 1, 8, 1);
        G1_PH(3, sb + 6, 2, 8, 1);
    }
    G1_PH(0, NS1_ - 1, 3, 8, 1);
    G1_PH(1, 0, 0, 8, 0);
    G1_PH(2, 0, 0, 4, 0);
    G1_PH(3, 0, 0, 0, 0);
#undef G1_STG
#undef G1_RD
#undef G1_MM
#undef G1_PH

    // ---- epilogue: silu(g)*u -> LDS transpose -> k-packet h_pk ----
    __syncthreads();
    const int q4 = lane >> 4;
    #pragma unroll
    for (int cfp = 0; cfp < 2; ++cfp) {
        int ml = (wid & 3) * 2 + cfp;
        int hcol = (bx * 8 + ml) * 16 + fr;
        float gs = scale[e * TWOI_ + hcol];
        float us = scale[e * TWOI_ + I_ + hcol];
        int cl = ml * 16 + fr;
        #pragma unroll
        for (int rf = 0; rf < 8; ++rf) {
            #pragma unroll
            for (int jj = 0; jj < 4; ++jj) {
                int row = wr128 + rf * 16 + q4 * 4 + jj;
                float gv = acc[rf][cfp * 2][jj] * gs;
                float uv = acc[rf][cfp * 2 + 1][jj] * us;
                float s = 1.f / (1.f + __expf(-gv));
                SM[row * 136 + cl] = f2bf(gv * s * uv);
            }
        }
    }
    __syncthreads();
    #pragma unroll
    for (int v = 0; v < 8; ++v) {
        int l = tid & 63;
        int w = tid >> 6;
        int o = w * 2 + (v & 1);
        int rloc = (v >> 1) * 64 + l;
        if (rloc < cn - row0) {
            int g = base + row0 + rloc;
            bf16x8 hv = *(const bf16x8*)&SM[rloc * 136 + o * 8];
            size_t dst = (size_t)(g >> 8) * HPBLK_
                       + (size_t)((bx * 4 + (o >> 2)) * 4 + (o & 3)) * 2048
                       + (size_t)(g & 255) * 8;
            *(bf16x8*)(h_pk + dst) = hv;
        }
    }
}

// ==================== GEMM2 ring-4 depth-3, coalesced store (no atomics) ====================
__global__ __launch_bounds__(512, 1) void gemm2s_kernel(
    const short* __restrict__ h_pk,     // k-packet A
    const short* __restrict__ wd,       // k-packet B
    const float* __restrict__ dscale,   // [E,H]
    const int* __restrict__ cnt, const int* __restrict__ off,
    const float* __restrict__ wts,
    short* __restrict__ dscr) {         // [NSLOT,H] bf16 per-slot result
    const int id = blockIdx.x;
    const int e = id & 7;
    const int j = id >> 3;
    const int bx = j >> 5;              // 0..15
    const int by = j & 31;
    int cn = cnt[e];
    int row0 = by * 256;
    if (row0 >= cn) return;
    int base = off[e];

    __shared__ __align__(16) short SM[65536];
    __shared__ float swt[256];

    int tid = threadIdx.x;
    if (tid < 256) {
        int r = row0 + tid;
        swt[tid] = (r < cn) ? wts[base + r] : 0.f;
    }
    __syncthreads();

    const int lane = tid & 63;
    const int wid = tid >> 6;
    const int wr128 = (wid >> 2) * 128;
    const int wc64 = (wid & 3) * 64;
    const int fr = lane & 15;
    const int kq = lane >> 4;

    const int srow = tid & 255;
    const int kgo2 = (tid >> 8) * 2;

    int ga = row0 + srow; if (ga >= cn) ga = cn - 1;
    ga += base;
    const size_t aoff = (size_t)(ga >> 8) * HPBLK_ + (size_t)(ga & 255) * 8;
    const size_t bstride = (size_t)H_ * 8;
    const short* bsrc = wd + (size_t)e * 224 * bstride + (size_t)(bx * 256 + srow) * 8;

    bf16x8 av[8], bv[4];
    f32x4 acc[8][4];
    #pragma unroll
    for (int i = 0; i < 8; ++i)
        #pragma unroll
        for (int jj = 0; jj < 4; ++jj) acc[i][jj] = f32x4{0.f, 0.f, 0.f, 0.f};

#define G2_STG(q, slot) do {                                              \
        _Pragma("unroll")                                                 \
        for (int p_ = 0; p_ < 2; ++p_)                                    \
            gld16(h_pk + aoff + (size_t)((q) * 4 + kgo2 + p_) * 2048,     \
                  &SM[(((slot) * 4 + kgo2 + p_) * 256 + srow) * 8]);      \
        _Pragma("unroll")                                                 \
        for (int p_ = 0; p_ < 2; ++p_)                                    \
            gld16(bsrc + (size_t)((q) * 4 + kgo2 + p_) * bstride,         \
                  &SM[32768 + (((slot) * 4 + kgo2 + p_) * 256 + srow) * 8]); \
    } while (0)
#define G2_RD(ss) do {                                                    \
        _Pragma("unroll") for (int i_ = 0; i_ < 8; ++i_)                  \
            av[i_] = *(const bf16x8*)&SM[(((ss) * 4 + kq) * 256 + wr128 + i_ * 16 + fr) * 8]; \
        _Pragma("unroll") for (int j_ = 0; j_ < 4; ++j_)                  \
            bv[j_] = *(const bf16x8*)&SM[32768 + (((ss) * 4 + kq) * 256 + wc64 + j_ * 16 + fr) * 8]; \
    } while (0)
#define G2_MM() do {                                                      \
        __builtin_amdgcn_s_setprio(1);                                    \
        _Pragma("unroll") for (int i_ = 0; i_ < 8; ++i_)                  \
        _Pragma("unroll") for (int j_ = 0; j_ < 4; ++j_)                  \
            acc[i_][j_] = __builtin_amdgcn_mfma_f32_16x16x32_bf16(av[i_], bv[j_], acc[i_][j_], 0, 0, 0); \
        __builtin_amdgcn_s_setprio(0);                                    \
    } while (0)
#define G2_PH(ss, q, qs, V, DOSTG) do {                                   \
        VMW(V);                                                           \
        __builtin_amdgcn_s_barrier();                                     \
        __builtin_amdgcn_sched_barrier(0);                                \
        if (DOSTG) G2_STG(q, qs);                                         \
        G2_RD(ss);                                                        \
        G2_MM();                                                          \
    } while (0)

    G2_STG(0, 0); G2_STG(1, 1); G2_STG(2, 2);
    for (int sb = 0; sb < NS2_ - 4; sb += 4) {
        G2_PH(0, sb + 3, 3, 8, 1);
        G2_PH(1, sb + 4, 0, 8, 1);
        G2_PH(2, sb + 5, 1, 8, 1);
        G2_PH(3, sb + 6, 2, 8, 1);
    }
    G2_PH(0, NS2_ - 1, 3, 8, 1);
    G2_PH(1, 0, 0, 8, 0);
    G2_PH(2, 0, 0, 4, 0);
    G2_PH(3, 0, 0, 0, 0);
#undef G2_STG
#undef G2_RD
#undef G2_MM
#undef G2_PH

    // ---- epilogue: scale -> LDS transpose -> coalesced bf16x8 store to dscr ----
    __syncthreads();
    const int q4 = lane >> 4;
    const int wn = wid & 3;
    #pragma unroll
    for (int pass = 0; pass < 2; ++pass) {
        if ((wn >> 1) == pass) {
            #pragma unroll
            for (int cf = 0; cf < 4; ++cf) {
                int colL = (wn & 1) * 64 + cf * 16 + fr;       // 0..127
                int col = bx * 256 + pass * 128 + colL;
                float ds = dscale[e * H_ + col];
                #pragma unroll
                for (int rf = 0; rf < 8; ++rf) {
                    #pragma unroll
                    for (int jj = 0; jj < 4; ++jj) {
                        int row = wr128 + rf * 16 + q4 * 4 + jj;
                        SM[row * 136 + colL] = f2bf(acc[rf][cf][jj] * ds * swt[row]);
                    }
                }
            }
        }
        __syncthreads();
        #pragma unroll
        for (int v = 0; v < 8; ++v) {
            int l = tid & 63;
            int w8 = tid >> 6;
            int o = w8 * 2 + (v & 1);          // 0..15
            int rloc = (v >> 1) * 64 + l;      // 0..255
            if (rloc < cn - row0) {
                bf16x8 hv = *(const bf16x8*)&SM[rloc * 136 + o * 8];
                *(bf16x8*)(dscr + (size_t)(base + row0 + rloc) * H_
                           + bx * 256 + pass * 128 + o * 8) = hv;
            }
        }
        __syncthreads();
    }
}

// ---------------- combine: out[t] = dscr[inv[2t]] + dscr[inv[2t+1]] ----------------
__global__ __launch_bounds__(256) void combine_kernel(
    const short* __restrict__ dscr, const int* __restrict__ inv,
    float* __restrict__ out) {
    int idx = blockIdx.x * 256 + threadIdx.x;   // 0 .. T*H/8-1
    int t = idx >> 9;                           // H/8 = 512 chunks per token
    int c8 = (idx & 511) * 8;
    int s0 = inv[t * 2], s1 = inv[t * 2 + 1];
    bf16x8 a = *(const bf16x8*)(dscr + (size_t)s0 * H_ + c8);
    bf16x8 b = *(const bf16x8*)(dscr + (size_t)s1 * H_ + c8);
    float4 o0, o1;
    o0.x = bf2f(a[0]) + bf2f(b[0]);
    o0.y = bf2f(a[1]) + bf2f(b[1]);
    o0.z = bf2f(a[2]) + bf2f(b[2]);
    o0.w = bf2f(a[3]) + bf2f(b[3]);
    o1.x = bf2f(a[4]) + bf2f(b[4]);
    o1.y = bf2f(a[5]) + bf2f(b[5]);
    o1.z = bf2f(a[6]) + bf2f(b[6]);
    o1.w = bf2f(a[7]) + bf2f(b[7]);
    *(float4*)(out + (size_t)t * H_ + c8) = o0;
    *(float4*)(out + (size_t)t * H_ + c8 + 4) = o1;
}

// ================= fallback path (fused int32 dequant, known-good) =================
__global__ __launch_bounds__(256) void gemm1_kernel(
    const float* __restrict__ x, const int* __restrict__ wq,
    const float* __restrict__ scale,
    const int* __restrict__ cnt, const int* __restrict__ off,
    const int* __restrict__ toks, short* __restrict__ h_ws) {
    int e = blockIdx.z;
    int cn = cnt[e];
    int row0 = blockIdx.y * 128;
    if (row0 >= cn) return;
    int base = off[e];
    int c0 = blockIdx.x * 64;
    __shared__ __align__(16) short As[4][128][8];
    __shared__ __align__(16) short Bg[4][64][8];
    __shared__ __align__(16) short Bu[4][64][8];
    __shared__ int stok[128];
    int tid = threadIdx.x;
    if (tid < 128) {
        int r = row0 + tid;
        stok[tid] = toks[base + (r < cn ? r : 0)];
    }
    __syncthreads();
    const int lane = tid & 63;
    const int wid = tid >> 6;
    const int wrow = (wid >> 1) * 64;
    const int wcc = (wid & 1) * 32;
    const int fr = lane & 15;
    const int kg = lane >> 4;
    f32x4 accg[4][2], accu[4][2];
    #pragma unroll
    for (int i = 0; i < 4; ++i)
        #pragma unroll
        for (int j = 0; j < 2; ++j) {
            accg[i][j] = f32x4{0.f, 0.f, 0.f, 0.f};
            accu[i][j] = f32x4{0.f, 0.f, 0.f, 0.f};
        }
    const int ar = tid & 127;
    const int akg = (tid >> 7) * 2;
    const int bc = tid & 63;
    const int bkg = (tid >> 6) & 3;
    const float* xrow = x + (size_t)stok[ar] * H_;
    const int* wg = wq + (size_t)e * H_ * TWOI_ + c0 + bc;
    const int* wu = wg + I_;
    for (int kk = 0; kk < H_; kk += 32) {
        {
            const float* xp = xrow + kk + akg * 8;
            #pragma unroll
            for (int p = 0; p < 2; ++p) {
                float4 f0 = *(const float4*)(xp + p * 8);
                float4 f1 = *(const float4*)(xp + p * 8 + 4);
                bf16x8 v;
                v[0] = f2bf(f0.x); v[1] = f2bf(f0.y); v[2] = f2bf(f0.z); v[3] = f2bf(f0.w);
                v[4] = f2bf(f1.x); v[5] = f2bf(f1.y); v[6] = f2bf(f1.z); v[7] = f2bf(f1.w);
                *(bf16x8*)&As[akg + p][ar][0] = v;
            }
        }
        {
            const int* wpg = wg + (size_t)(kk + bkg * 8) * TWOI_;
            const int* wpu = wu + (size_t)(kk + bkg * 8) * TWOI_;
            bf16x8 vg, vu;
            #pragma unroll
            for (int j = 0; j < 8; ++j) {
                vg[j] = f2bf((float)wpg[(size_t)j * TWOI_] - 128.f);
                vu[j] = f2bf((float)wpu[(size_t)j * TWOI_] - 128.f);
            }
            *(bf16x8*)&Bg[bkg][bc][0] = vg;
            *(bf16x8*)&Bu[bkg][bc][0] = vu;
        }
        __syncthreads();
        bf16x8 a[4], bg[2], bu[2];
        #pragma unroll
        for (int rf = 0; rf < 4; ++rf) a[rf] = *(const bf16x8*)&As[kg][wrow + rf * 16 + fr][0];
        #pragma unroll
        for (int cf = 0; cf < 2; ++cf) {
            bg[cf] = *(const bf16x8*)&Bg[kg][wcc + cf * 16 + fr][0];
            bu[cf] = *(const bf16x8*)&Bu[kg][wcc + cf * 16 + fr][0];
        }
        #pragma unroll
        for (int rf = 0; rf < 4; ++rf)
            #pragma unroll
            for (int cf = 0; cf < 2; ++cf) {
                accg[rf][cf] = __builtin_amdgcn_mfma_f32_16x16x32_bf16(a[rf], bg[cf], accg[rf][cf], 0, 0, 0);
                accu[rf][cf] = __builtin_amdgcn_mfma_f32_16x16x32_bf16(a[rf], bu[cf], accu[rf][cf], 0, 0, 0);
            }
        __syncthreads();
    }
    const int q4 = lane >> 4;
    #pragma unroll
    for (int cf = 0; cf < 2; ++cf) {
        int col = c0 + wcc + cf * 16 + fr;
        float gs = scale[e * TWOI_ + col];
        float us = scale[e * TWOI_ + I_ + col];
        #pragma unroll
        for (int rf = 0; rf < 4; ++rf) {
            #pragma unroll
            for (int j = 0; j < 4; ++j) {
                int row = wrow + rf * 16 + q4 * 4 + j;
                if (row0 + row < cn) {
                    float gv = accg[rf][cf][j] * gs;
                    float uv = accu[rf][cf][j] * us;
                    float s = 1.f / (1.f + __expf(-gv));
                    h_ws[(size_t)(base + row0 + row) * I_ + col] = f2bf(gv * s * uv);
                }
            }
        }
    }
}

__global__ __launch_bounds__(256) void gemm2_kernel(
    const short* __restrict__ h_ws, const int* __restrict__ wq,
    const float* __restrict__ dscale,
    const int* __restrict__ cnt, const int* __restrict__ off,
    const int* __restrict__ toks, const float* __restrict__ wts,
    float* __restrict__ out) {
    int e = blockIdx.z;
    int cn = cnt[e];
    int row0 = blockIdx.y * 128;
    if (row0 >= cn) return;
    int base = off[e];
    int c0 = blockIdx.x * 128;
    __shared__ __align__(16) short As[4][128][8];
    __shared__ __align__(16) short Bs[4][128][8];
    __shared__ int stok[128];
    __shared__ float swt[128];
    int tid = threadIdx.x;
    if (tid < 128) {
        int r = row0 + tid;
        int idx = base + (r < cn ? r : 0);
        stok[tid] = toks[idx];
        swt[tid] = (r < cn) ? wts[idx] : 0.f;
    }
    __syncthreads();
    const int lane = tid & 63;
    const int wid = tid >> 6;
    const int wrow = (wid >> 1) * 64;
    const int wcc = (wid & 1) * 64;
    const int fr = lane & 15;
    const int kg = lane >> 4;
    f32x4 acc[4][4];
    #pragma unroll
    for (int i = 0; i < 4; ++i)
        #pragma unroll
        for (int j = 0; j < 4; ++j) acc[i][j] = f32x4{0.f, 0.f, 0.f, 0.f};
    const int ar = tid & 127;
    const int akg = (tid >> 7) * 2;
    const int bc = tid & 127;
    const int bkg2 = (tid >> 7) * 2;
    const short* hrow = h_ws + (size_t)(base + ((row0 + ar) < cn ? row0 + ar : 0)) * I_;
    const int* wcol = wq + (size_t)e * I_ * H_ + c0 + bc;
    for (int kk = 0; kk < I_; kk += 32) {
        #pragma unroll
        for (int p = 0; p < 2; ++p) {
            *(bf16x8*)&As[akg + p][ar][0] = *(const bf16x8*)(hrow + kk + (akg + p) * 8);
        }
        #pragma unroll
        for (int p = 0; p < 2; ++p) {
            const int* wp = wcol + (size_t)(kk + (bkg2 + p) * 8) * H_;
            bf16x8 v;
            #pragma unroll
            for (int j = 0; j < 8; ++j) v[j] = f2bf((float)wp[(size_t)j * H_] - 128.f);
            *(bf16x8*)&Bs[bkg2 + p][bc][0] = v;
        }
        __syncthreads();
        bf16x8 a[4], b[4];
        #pragma unroll
        for (int rf = 0; rf < 4; ++rf) a[rf] = *(const bf16x8*)&As[kg][wrow + rf * 16 + fr][0];
        #pragma unroll
        for (int cf = 0; cf < 4; ++cf) b[cf] = *(const bf16x8*)&Bs[kg][wcc + cf * 16 + fr][0];
        #pragma unroll
        for (int rf = 0; rf < 4; ++rf)
            #pragma unroll
            for (int cf = 0; cf < 4; ++cf)
                acc[rf][cf] = __builtin_amdgcn_mfma_f32_16x16x32_bf16(a[rf], b[cf], acc[rf][cf], 0, 0, 0);
        __syncthreads();
    }
    const int q4 = lane >> 4;
    #pragma unroll
    for (int cf = 0; cf < 4; ++cf) {
        int col = c0 + wcc + cf * 16 + fr;
        float ds = dscale[e * H_ + col];
        #pragma unroll
        for (int rf = 0; rf < 4; ++rf) {
            #pragma unroll
            for (int j = 0; j < 4; ++j) {
                int row = wrow + rf * 16 + q4 * 4 + j;
                if (row0 + row < cn) {
                    float v = acc[rf][cf][j] * ds * swt[row];
                    atomicAdd(&out[(size_t)stok[row] * H_ + col], v);
                }
            }
        }
    }
}

extern "C" void kernel_launch(void* const* d_in, const int* in_sizes, int n_in,
                              void* d_out, int out_size, void* d_ws, size_t ws_size,
                              hipStream_t stream) {
    const float* x     = (const float*)d_in[0];
    const float* aff   = (const float*)d_in[1];
    const int*   guq   = (const int*)d_in[2];
    const float* gus   = (const float*)d_in[3];
    const int*   dwq   = (const int*)d_in[4];
    const float* dsc   = (const float*)d_in[5];
    const int*   eidx  = (const int*)d_in[6];
    float* out = (float*)d_out;

    char* ws = (char*)d_ws;
    int* cnt = (int*)ws;
    int* off = cnt + 8;
    int* toks = (int*)(ws + 64);
    float* wts = (float*)(ws + 64 + NSLOT_ * 4);
    int* inv  = (int*)(ws + 64 + NSLOT_ * 8);

    const size_t off_h  = (size_t)1 << 20;
    const size_t sz_h   = (size_t)NSLOT_ * I_ * 2;          // 29.36 MB (h_pk / h_ws)
    const size_t off_xg = off_h + sz_h;
    const size_t sz_xg  = (size_t)NSLOT_ * H_ * 2;          // 67.1 MB (xg, reused as dscr)
    const size_t off_gu = off_xg + sz_xg;
    const size_t sz_gu  = (size_t)E_ * 512 * TWOI_ * 8 * 2; // 234.9 MB
    const size_t off_dn = off_gu + sz_gu;
    const size_t sz_dn  = (size_t)E_ * 224 * H_ * 8 * 2;    // 117.4 MB
    const size_t NEED   = off_dn + sz_dn;                   // ~450 MB

    short* h_ws = (short*)(ws + off_h);

    route_kernel<<<1, 1024, 0, stream>>>(eidx, aff, cnt, off, toks, wts, inv);

    if (ws_size >= NEED) {
        short* xg   = (short*)(ws + off_xg);    // also dscr after gemm1r
        short* wgur = (short*)(ws + off_gu);
        short* wdr  = (short*)(ws + off_dn);

        gather_x_kernel<<<256, 256, 0, stream>>>(x, toks, xg);
        dim3 rg1(TWOI_ / 32, H_ / 64, E_);
        repack_gu_kernel<<<rg1, 256, 0, stream>>>(guq, wgur);
        dim3 rg2(H_ / 32, I_ / 64, E_);
        repack_dn_kernel<<<rg2, 256, 0, stream>>>(dwq, wdr);

        gemm1r_kernel<<<(TWOI_ / 256) * (NSLOT_ / 256) * E_, 512, 0, stream>>>(
            xg, wgur, gus, cnt, off, h_ws /* = h_pk */);
        // xg is dead now; reuse as dscr
        gemm2s_kernel<<<(H_ / 256) * (NSLOT_ / 256) * E_, 512, 0, stream>>>(
            h_ws, wdr, dsc, cnt, off, wts, xg /* dscr */);
        combine_kernel<<<(T_ * H_ / 8) / 256, 256, 0, stream>>>(xg, inv, out);
    } else {
        hipMemsetAsync(d_out, 0, (size_t)out_size * sizeof(float), stream);
        dim3 g1(I_ / 64, NSLOT_ / 128, E_);
        gemm1_kernel<<<g1, 256, 0, stream>>>(x, guq, gus, cnt, off, toks, h_ws);
        dim3 g2(H_ / 128, NSLOT_ / 128, E_);
        gemm2_kernel<<<g2, 256, 0, stream>>>(h_ws, dwq, dsc, cnt, off, toks, wts, out);
    }
}

// Round 10
// 840.569 us; speedup vs baseline: 1.6079x; 1.1111x over previous
//
#include <hip/hip_runtime.h>
#include <hip/hip_bf16.h>
#include <stdint.h>

#define E_ 8
#define H_ 4096
#define I_ 1792
#define TWOI_ 3584
#define T_ 4096
#define NSLOT_ 8192
#define NRBMAX_ 40        /* max padded 256-slot blocks */
#define NS1_ 128          /* H_/32 k-slices */
#define NS2_ 56           /* I_/32 k-slices */
#define XGBLK_ 1048576    /* shorts per xg slot-block: 128*4*256*8 */
#define HPBLK_ 458752     /* shorts per h_pk slot-block: 56*4*256*8 */

typedef __attribute__((ext_vector_type(4))) float f32x4;
typedef __attribute__((ext_vector_type(8))) short bf16x8;

static __device__ __forceinline__ short f2bf(float f) {
    unsigned u = __builtin_bit_cast(unsigned, f);
    u += 0x7FFF + ((u >> 16) & 1);   // round-to-nearest-even
    return (short)(u >> 16);
}

static __device__ __forceinline__ float bf2f(short s) {
    unsigned u = ((unsigned)(unsigned short)s) << 16;
    return __builtin_bit_cast(float, u);
}

static __device__ __forceinline__ void gld16(const void* g, void* l) {
    __builtin_amdgcn_global_load_lds(
        (const __attribute__((address_space(1))) void*)g,
        (__attribute__((address_space(3))) void*)l, 16, 0, 0);
}

#define VMW_(n) asm volatile("s_waitcnt vmcnt(" #n ")" ::: "memory")
#define VMW(n) VMW_(n)

// ---------------- routing: padded per-expert lists + row-block table ----------------
__global__ void route_kernel(const int* __restrict__ eidx,
                             const float* __restrict__ aff,
                             int* __restrict__ cnt, int* __restrict__ poff,
                             int* __restrict__ rbE, int* __restrict__ nrbG,
                             int* __restrict__ toks, float* __restrict__ wts,
                             int* __restrict__ inv) {
    __shared__ int scnt[E_];
    __shared__ int spoff[E_];
    __shared__ int scur[E_];
    int tid = threadIdx.x;
    if (tid < E_) scnt[tid] = 0;
    __syncthreads();
    for (int s = tid; s < NSLOT_; s += blockDim.x) {
        atomicAdd(&scnt[eidx[s]], 1);
    }
    __syncthreads();
    if (tid == 0) {
        int acc = 0, rb = 0;
        for (int e = 0; e < E_; ++e) {
            int c = scnt[e];
            cnt[e] = c; poff[e] = acc; spoff[e] = acc;
            int nb = (c + 255) >> 8;
            for (int i = 0; i < nb; ++i) rbE[rb++] = e;
            acc += nb << 8;
        }
        *nrbG = rb;
        for (int i = rb; i < NRBMAX_; ++i) rbE[i] = -1;
    }
    __syncthreads();
    if (tid < E_) scur[tid] = spoff[tid];
    __syncthreads();
    for (int s = tid; s < NSLOT_; s += blockDim.x) {
        int t = s >> 1;
        int e0 = eidx[t * 2], e1 = eidx[t * 2 + 1];
        float a0 = aff[t * E_ + e0], a1 = aff[t * E_ + e1];
        int k = s & 1;
        int e = k ? e1 : e0;
        float w = (k ? a1 : a0) / (a0 + a1);
        int pos = atomicAdd(&scur[e], 1);
        toks[pos] = t;
        wts[pos] = w;
        inv[s] = pos;
    }
    __syncthreads();
    // pads: replicate last real token, weight 0
    for (int e = 0; e < E_; ++e) {
        int c = scnt[e];
        if (c == 0) continue;
        int padded = ((c + 255) >> 8) << 8;
        int lastTok = toks[spoff[e] + c - 1];
        for (int p = c + tid; p < padded; p += blockDim.x) {
            toks[spoff[e] + p] = lastTok;
            wts[spoff[e] + p] = 0.f;
        }
    }
}

// ---------------- gather x -> k-packet bf16 xg[sb][128][4][256][8] ----------------
__global__ __launch_bounds__(256) void gather_x_kernel(const float* __restrict__ x,
                                                       const int* __restrict__ toks,
                                                       const int* __restrict__ nrbG,
                                                       short* __restrict__ xg) {
    int blk = blockIdx.x >> 3;        // 0..39
    if (blk >= *nrbG) return;
    int sc = blockIdx.x & 7;          // slice chunk (16 slices)
    int row = threadIdx.x;            // 0..255
    int g = blk * 256 + row;
    const float* src = x + (size_t)toks[g] * H_ + sc * 512;
    short* dstbase = xg + (size_t)blk * XGBLK_ + (size_t)row * 8;
    for (int s = 0; s < 16; ++s) {
        int slice = sc * 16 + s;
        #pragma unroll
        for (int kg = 0; kg < 4; ++kg) {
            float4 f0 = *(const float4*)(src + s * 32 + kg * 8);
            float4 f1 = *(const float4*)(src + s * 32 + kg * 8 + 4);
            bf16x8 v;
            v[0] = f2bf(f0.x); v[1] = f2bf(f0.y); v[2] = f2bf(f0.z); v[3] = f2bf(f0.w);
            v[4] = f2bf(f1.x); v[5] = f2bf(f1.y); v[6] = f2bf(f1.z); v[7] = f2bf(f1.w);
            *(bf16x8*)(dstbase + (size_t)(slice * 4 + kg) * 2048) = v;
        }
    }
}

// ---------------- coalesced weight repacks (LDS transpose) ----------------
__global__ __launch_bounds__(256) void repack_gu_kernel(const int* __restrict__ wq,
                                                        short* __restrict__ out) {
    __shared__ short sm[64][33];
    int e = blockIdx.z;
    int by = blockIdx.y;              // 0..63
    int bx = blockIdx.x;              // 0..111
    int tid = threadIdx.x;
    {
        int rw = tid >> 2;
        int q = tid & 3;
        int ocol = (q < 2) ? (bx * 16 + q * 8) : (I_ + bx * 16 + (q - 2) * 8);
        const int* src = wq + ((size_t)e * H_ + by * 64 + rw) * TWOI_ + ocol;
        #pragma unroll
        for (int i = 0; i < 8; ++i)
            sm[rw][q * 8 + i] = f2bf((float)(src[i] - 128));
    }
    __syncthreads();
    {
        int yl = tid >> 5;
        int c = tid & 31;
        bf16x8 v;
        #pragma unroll
        for (int i = 0; i < 8; ++i) v[i] = sm[yl * 8 + i][c];
        *(bf16x8*)(out + (((size_t)e * 512 + by * 8 + yl) * TWOI_ + bx * 32 + c) * 8) = v;
    }
}

__global__ __launch_bounds__(256) void repack_dn_kernel(const int* __restrict__ wq,
                                                        short* __restrict__ out) {
    __shared__ short sm[64][33];
    int e = blockIdx.z;
    int by = blockIdx.y;              // 0..27
    int bx = blockIdx.x;              // 0..127
    int tid = threadIdx.x;
    {
        int rw = tid >> 2;
        int q = tid & 3;
        const int* src = wq + ((size_t)e * I_ + by * 64 + rw) * H_ + bx * 32 + q * 8;
        #pragma unroll
        for (int i = 0; i < 8; ++i)
            sm[rw][q * 8 + i] = f2bf((float)(src[i] - 128));
    }
    __syncthreads();
    {
        int yl = tid >> 5;
        int c = tid & 31;
        bf16x8 v;
        #pragma unroll
        for (int i = 0; i < 8; ++i) v[i] = sm[yl * 8 + i][c];
        *(bf16x8*)(out + (((size_t)e * 224 + by * 8 + yl) * H_ + bx * 32 + c) * 8) = v;
    }
}

// ==================== GEMM1 ring-4 depth-3, uniform padded blocks ====================
__global__ __launch_bounds__(512, 1) void gemm1r_kernel(
    const short* __restrict__ xg,       // k-packet A [sb][...]
    const short* __restrict__ wgu,      // k-packet B (interleaved g/u)
    const float* __restrict__ scale,    // [E,2I]
    const int* __restrict__ rbE, const int* __restrict__ nrbG,
    short* __restrict__ h_pk) {         // k-packet h [sb][...]
    // XCD-chunked decode: 560 blocks = 8 xcd * 70; sb-major within xcd
    const int xcd = blockIdx.x & 7;
    const int loc = blockIdx.x >> 3;          // 0..69
    const int work = xcd * 70 + loc;          // 0..559
    const int sb = work / 14;                 // 0..39
    const int bx = work % 14;
    if (sb >= *nrbG) return;
    const int e = rbE[sb];

    __shared__ __align__(16) short SM[65536];   // A: [0,32768) B: [32768,65536)

    int tid = threadIdx.x;
    const int lane = tid & 63;
    const int wid = tid >> 6;
    const int wr128 = (wid >> 2) * 128;
    const int wc64 = (wid & 3) * 64;
    const int fr = lane & 15;
    const int kq = lane >> 4;

    const int srow = tid & 255;
    const int kgo2 = (tid >> 8) * 2;    // 0 or 2

    const size_t aoff = (size_t)sb * XGBLK_ + (size_t)srow * 8;
    const size_t bstride = (size_t)TWOI_ * 8;
    const short* bsrc = wgu + (size_t)e * 512 * bstride + (size_t)(bx * 256 + srow) * 8;

    bf16x8 av[8], bv[4];
    f32x4 acc[8][4];
    #pragma unroll
    for (int i = 0; i < 8; ++i)
        #pragma unroll
        for (int jj = 0; jj < 4; ++jj) acc[i][jj] = f32x4{0.f, 0.f, 0.f, 0.f};

#define G1_STG(q, slot) do {                                              \
        _Pragma("unroll")                                                 \
        for (int p_ = 0; p_ < 2; ++p_)                                    \
            gld16(xg + aoff + (size_t)((q) * 4 + kgo2 + p_) * 2048,       \
                  &SM[(((slot) * 4 + kgo2 + p_) * 256 + srow) * 8]);      \
        _Pragma("unroll")                                                 \
        for (int p_ = 0; p_ < 2; ++p_)                                    \
            gld16(bsrc + (size_t)((q) * 4 + kgo2 + p_) * bstride,         \
                  &SM[32768 + (((slot) * 4 + kgo2 + p_) * 256 + srow) * 8]); \
    } while (0)
#define G1_RD(ss) do {                                                    \
        _Pragma("unroll") for (int i_ = 0; i_ < 8; ++i_)                  \
            av[i_] = *(const bf16x8*)&SM[(((ss) * 4 + kq) * 256 + wr128 + i_ * 16 + fr) * 8]; \
        _Pragma("unroll") for (int j_ = 0; j_ < 4; ++j_)                  \
            bv[j_] = *(const bf16x8*)&SM[32768 + (((ss) * 4 + kq) * 256 + wc64 + j_ * 16 + fr) * 8]; \
    } while (0)
#define G1_MM() do {                                                      \
        __builtin_amdgcn_s_setprio(1);                                    \
        _Pragma("unroll") for (int i_ = 0; i_ < 8; ++i_)                  \
        _Pragma("unroll") for (int j_ = 0; j_ < 4; ++j_)                  \
            acc[i_][j_] = __builtin_amdgcn_mfma_f32_16x16x32_bf16(av[i_], bv[j_], acc[i_][j_], 0, 0, 0); \
        __builtin_amdgcn_s_setprio(0);                                    \
    } while (0)
#define G1_PH(ss, q, qs, V, DOSTG) do {                                   \
        VMW(V);                                                           \
        __builtin_amdgcn_s_barrier();                                     \
        __builtin_amdgcn_sched_barrier(0);                                \
        if (DOSTG) G1_STG(q, qs);                                         \
        G1_RD(ss);                                                        \
        G1_MM();                                                          \
    } while (0)

    G1_STG(0, 0); G1_STG(1, 1); G1_STG(2, 2);
    for (int sbi = 0; sbi < NS1_ - 4; sbi += 4) {
        G1_PH(0, sbi + 3, 3, 8, 1);
        G1_PH(1, sbi + 4, 0, 8, 1);
        G1_PH(2, sbi + 5, 1, 8, 1);
        G1_PH(3, sbi + 6, 2, 8, 1);
    }
    G1_PH(0, NS1_ - 1, 3, 8, 1);
    G1_PH(1, 0, 0, 8, 0);
    G1_PH(2, 0, 0, 4, 0);
    G1_PH(3, 0, 0, 0, 0);
#undef G1_STG
#undef G1_RD
#undef G1_MM
#undef G1_PH

    // ---- epilogue: silu(g)*u -> LDS transpose -> k-packet h_pk (uniform) ----
    __syncthreads();
    const int q4 = lane >> 4;
    #pragma unroll
    for (int cfp = 0; cfp < 2; ++cfp) {
        int ml = (wid & 3) * 2 + cfp;
        int hcol = (bx * 8 + ml) * 16 + fr;
        float gs = scale[e * TWOI_ + hcol];
        float us = scale[e * TWOI_ + I_ + hcol];
        int cl = ml * 16 + fr;
        #pragma unroll
        for (int rf = 0; rf < 8; ++rf) {
            #pragma unroll
            for (int jj = 0; jj < 4; ++jj) {
                int row = wr128 + rf * 16 + q4 * 4 + jj;
                float gv = acc[rf][cfp * 2][jj] * gs;
                float uv = acc[rf][cfp * 2 + 1][jj] * us;
                float s = 1.f / (1.f + __expf(-gv));
                SM[row * 136 + cl] = f2bf(gv * s * uv);
            }
        }
    }
    __syncthreads();
    #pragma unroll
    for (int v = 0; v < 8; ++v) {
        int l = tid & 63;
        int w = tid >> 6;
        int o = w * 2 + (v & 1);
        int rloc = (v >> 1) * 64 + l;
        bf16x8 hv = *(const bf16x8*)&SM[rloc * 136 + o * 8];
        size_t dst = (size_t)sb * HPBLK_
                   + (size_t)((bx * 4 + (o >> 2)) * 4 + (o & 3)) * 2048
                   + (size_t)rloc * 8;
        *(bf16x8*)(h_pk + dst) = hv;
    }
}

// ==================== GEMM2 ring-4 depth-3, uniform padded blocks ====================
__global__ __launch_bounds__(512, 1) void gemm2s_kernel(
    const short* __restrict__ h_pk,     // k-packet A [sb][...]
    const short* __restrict__ wd,       // k-packet B
    const float* __restrict__ dscale,   // [E,H]
    const int* __restrict__ rbE, const int* __restrict__ nrbG,
    const float* __restrict__ wts,
    short* __restrict__ dscr) {         // [padded slots, H] bf16
    const int xcd = blockIdx.x & 7;
    const int loc = blockIdx.x >> 3;          // 0..79
    const int work = xcd * 80 + loc;          // 0..639
    const int sb = work / 16;                 // 0..39
    const int bx = work % 16;
    if (sb >= *nrbG) return;
    const int e = rbE[sb];

    __shared__ __align__(16) short SM[65536];
    __shared__ float swt[256];

    int tid = threadIdx.x;
    if (tid < 256) swt[tid] = wts[sb * 256 + tid];
    __syncthreads();

    const int lane = tid & 63;
    const int wid = tid >> 6;
    const int wr128 = (wid >> 2) * 128;
    const int wc64 = (wid & 3) * 64;
    const int fr = lane & 15;
    const int kq = lane >> 4;

    const int srow = tid & 255;
    const int kgo2 = (tid >> 8) * 2;

    const size_t aoff = (size_t)sb * HPBLK_ + (size_t)srow * 8;
    const size_t bstride = (size_t)H_ * 8;
    const short* bsrc = wd + (size_t)e * 224 * bstride + (size_t)(bx * 256 + srow) * 8;

    bf16x8 av[8], bv[4];
    f32x4 acc[8][4];
    #pragma unroll
    for (int i = 0; i < 8; ++i)
        #pragma unroll
        for (int jj = 0; jj < 4; ++jj) acc[i][jj] = f32x4{0.f, 0.f, 0.f, 0.f};

#define G2_STG(q, slot) do {                                              \
        _Pragma("unroll")                                                 \
        for (int p_ = 0; p_ < 2; ++p_)                                    \
            gld16(h_pk + aoff + (size_t)((q) * 4 + kgo2 + p_) * 2048,     \
                  &SM[(((slot) * 4 + kgo2 + p_) * 256 + srow) * 8]);      \
        _Pragma("unroll")                                                 \
        for (int p_ = 0; p_ < 2; ++p_)                                    \
            gld16(bsrc + (size_t)((q) * 4 + kgo2 + p_) * bstride,         \
                  &SM[32768 + (((slot) * 4 + kgo2 + p_) * 256 + srow) * 8]); \
    } while (0)
#define G2_RD(ss) do {                                                    \
        _Pragma("unroll") for (int i_ = 0; i_ < 8; ++i_)                  \
            av[i_] = *(const bf16x8*)&SM[(((ss) * 4 + kq) * 256 + wr128 + i_ * 16 + fr) * 8]; \
        _Pragma("unroll") for (int j_ = 0; j_ < 4; ++j_)                  \
            bv[j_] = *(const bf16x8*)&SM[32768 + (((ss) * 4 + kq) * 256 + wc64 + j_ * 16 + fr) * 8]; \
    } while (0)
#define G2_MM() do {                                                      \
        __builtin_amdgcn_s_setprio(1);                                    \
        _Pragma("unroll") for (int i_ = 0; i_ < 8; ++i_)                  \
        _Pragma("unroll") for (int j_ = 0; j_ < 4; ++j_)                  \
            acc[i_][j_] = __builtin_amdgcn_mfma_f32_16x16x32_bf16(av[i_], bv[j_], acc[i_][j_], 0, 0, 0); \
        __builtin_amdgcn_s_setprio(0);                                    \
    } while (0)
#define G2_PH(ss, q, qs, V, DOSTG) do {                                   \
        VMW(V);                                                           \
        __builtin_amdgcn_s_barrier();                                     \
        __builtin_amdgcn_sched_barrier(0);                                \
        if (DOSTG) G2_STG(q, qs);                                         \
        G2_RD(ss);                                                        \
        G2_MM();                                                          \
    } while (0)

    G2_STG(0, 0); G2_STG(1, 1); G2_STG(2, 2);
    for (int sbi = 0; sbi < NS2_ - 4; sbi += 4) {
        G2_PH(0, sbi + 3, 3, 8, 1);
        G2_PH(1, sbi + 4, 0, 8, 1);
        G2_PH(2, sbi + 5, 1, 8, 1);
        G2_PH(3, sbi + 6, 2, 8, 1);
    }
    G2_PH(0, NS2_ - 1, 3, 8, 1);
    G2_PH(1, 0, 0, 8, 0);
    G2_PH(2, 0, 0, 4, 0);
    G2_PH(3, 0, 0, 0, 0);
#undef G2_STG
#undef G2_RD
#undef G2_MM
#undef G2_PH

    // ---- epilogue: scale -> LDS transpose -> coalesced bf16x8 store (uniform) ----
    __syncthreads();
    const int q4 = lane >> 4;
    const int wn = wid & 3;
    #pragma unroll
    for (int pass = 0; pass < 2; ++pass) {
        if ((wn >> 1) == pass) {
            #pragma unroll
            for (int cf = 0; cf < 4; ++cf) {
                int colL = (wn & 1) * 64 + cf * 16 + fr;       // 0..127
                int col = bx * 256 + pass * 128 + colL;
                float ds = dscale[e * H_ + col];
                #pragma unroll
                for (int rf = 0; rf < 8; ++rf) {
                    #pragma unroll
                    for (int jj = 0; jj < 4; ++jj) {
                        int row = wr128 + rf * 16 + q4 * 4 + jj;
                        SM[row * 136 + colL] = f2bf(acc[rf][cf][jj] * ds * swt[row]);
                    }
                }
            }
        }
        __syncthreads();
        #pragma unroll
        for (int v = 0; v < 8; ++v) {
            int l = tid & 63;
            int w8 = tid >> 6;
            int o = w8 * 2 + (v & 1);          // 0..15
            int rloc = (v >> 1) * 64 + l;      // 0..255
            bf16x8 hv = *(const bf16x8*)&SM[rloc * 136 + o * 8];
            *(bf16x8*)(dscr + (size_t)(sb * 256 + rloc) * H_
                       + bx * 256 + pass * 128 + o * 8) = hv;
        }
        __syncthreads();
    }
}

// ---------------- combine: out[t] = dscr[inv[2t]] + dscr[inv[2t+1]] ----------------
__global__ __launch_bounds__(256) void combine_kernel(
    const short* __restrict__ dscr, const int* __restrict__ inv,
    float* __restrict__ out) {
    int idx = blockIdx.x * 256 + threadIdx.x;   // 0 .. T*H/8-1
    int t = idx >> 9;                           // H/8 = 512 chunks per token
    int c8 = (idx & 511) * 8;
    int s0 = inv[t * 2], s1 = inv[t * 2 + 1];
    bf16x8 a = *(const bf16x8*)(dscr + (size_t)s0 * H_ + c8);
    bf16x8 b = *(const bf16x8*)(dscr + (size_t)s1 * H_ + c8);
    float4 o0, o1;
    o0.x = bf2f(a[0]) + bf2f(b[0]);
    o0.y = bf2f(a[1]) + bf2f(b[1]);
    o0.z = bf2f(a[2]) + bf2f(b[2]);
    o0.w = bf2f(a[3]) + bf2f(b[3]);
    o1.x = bf2f(a[4]) + bf2f(b[4]);
    o1.y = bf2f(a[5]) + bf2f(b[5]);
    o1.z = bf2f(a[6]) + bf2f(b[6]);
    o1.w = bf2f(a[7]) + bf2f(b[7]);
    *(float4*)(out + (size_t)t * H_ + c8) = o0;
    *(float4*)(out + (size_t)t * H_ + c8 + 4) = o1;
}

// ================= fallback path (fused int32 dequant, known-good) =================
__global__ __launch_bounds__(256) void gemm1_kernel(
    const float* __restrict__ x, const int* __restrict__ wq,
    const float* __restrict__ scale,
    const int* __restrict__ cnt, const int* __restrict__ off,
    const int* __restrict__ toks, short* __restrict__ h_ws) {
    int e = blockIdx.z;
    int cn = cnt[e];
    int row0 = blockIdx.y * 128;
    if (row0 >= cn) return;
    int base = off[e];
    int c0 = blockIdx.x * 64;
    __shared__ __align__(16) short As[4][128][8];
    __shared__ __align__(16) short Bg[4][64][8];
    __shared__ __align__(16) short Bu[4][64][8];
    __shared__ int stok[128];
    int tid = threadIdx.x;
    if (tid < 128) {
        int r = row0 + tid;
        stok[tid] = toks[base + (r < cn ? r : 0)];
    }
    __syncthreads();
    const int lane = tid & 63;
    const int wid = tid >> 6;
    const int wrow = (wid >> 1) * 64;
    const int wcc = (wid & 1) * 32;
    const int fr = lane & 15;
    const int kg = lane >> 4;
    f32x4 accg[4][2], accu[4][2];
    #pragma unroll
    for (int i = 0; i < 4; ++i)
        #pragma unroll
        for (int j = 0; j < 2; ++j) {
            accg[i][j] = f32x4{0.f, 0.f, 0.f, 0.f};
            accu[i][j] = f32x4{0.f, 0.f, 0.f, 0.f};
        }
    const int ar = tid & 127;
    const int akg = (tid >> 7) * 2;
    const int bc = tid & 63;
    const int bkg = (tid >> 6) & 3;
    const float* xrow = x + (size_t)stok[ar] * H_;
    const int* wg = wq + (size_t)e * H_ * TWOI_ + c0 + bc;
    const int* wu = wg + I_;
    for (int kk = 0; kk < H_; kk += 32) {
        {
            const float* xp = xrow + kk + akg * 8;
            #pragma unroll
            for (int p = 0; p < 2; ++p) {
                float4 f0 = *(const float4*)(xp + p * 8);
                float4 f1 = *(const float4*)(xp + p * 8 + 4);
                bf16x8 v;
                v[0] = f2bf(f0.x); v[1] = f2bf(f0.y); v[2] = f2bf(f0.z); v[3] = f2bf(f0.w);
                v[4] = f2bf(f1.x); v[5] = f2bf(f1.y); v[6] = f2bf(f1.z); v[7] = f2bf(f1.w);
                *(bf16x8*)&As[akg + p][ar][0] = v;
            }
        }
        {
            const int* wpg = wg + (size_t)(kk + bkg * 8) * TWOI_;
            const int* wpu = wu + (size_t)(kk + bkg * 8) * TWOI_;
            bf16x8 vg, vu;
            #pragma unroll
            for (int j = 0; j < 8; ++j) {
                vg[j] = f2bf((float)wpg[(size_t)j * TWOI_] - 128.f);
                vu[j] = f2bf((float)wpu[(size_t)j * TWOI_] - 128.f);
            }
            *(bf16x8*)&Bg[bkg][bc][0] = vg;
            *(bf16x8*)&Bu[bkg][bc][0] = vu;
        }
        __syncthreads();
        bf16x8 a[4], bg[2], bu[2];
        #pragma unroll
        for (int rf = 0; rf < 4; ++rf) a[rf] = *(const bf16x8*)&As[kg][wrow + rf * 16 + fr][0];
        #pragma unroll
        for (int cf = 0; cf < 2; ++cf) {
            bg[cf] = *(const bf16x8*)&Bg[kg][wcc + cf * 16 + fr][0];
            bu[cf] = *(const bf16x8*)&Bu[kg][wcc + cf * 16 + fr][0];
        }
        #pragma unroll
        for (int rf = 0; rf < 4; ++rf)
            #pragma unroll
            for (int cf = 0; cf < 2; ++cf) {
                accg[rf][cf] = __builtin_amdgcn_mfma_f32_16x16x32_bf16(a[rf], bg[cf], accg[rf][cf], 0, 0, 0);
                accu[rf][cf] = __builtin_amdgcn_mfma_f32_16x16x32_bf16(a[rf], bu[cf], accu[rf][cf], 0, 0, 0);
            }
        __syncthreads();
    }
    const int q4 = lane >> 4;
    #pragma unroll
    for (int cf = 0; cf < 2; ++cf) {
        int col = c0 + wcc + cf * 16 + fr;
        float gs = scale[e * TWOI_ + col];
        float us = scale[e * TWOI_ + I_ + col];
        #pragma unroll
        for (int rf = 0; rf < 4; ++rf) {
            #pragma unroll
            for (int j = 0; j < 4; ++j) {
                int row = wrow + rf * 16 + q4 * 4 + j;
                if (row0 + row < cn) {
                    float gv = accg[rf][cf][j] * gs;
                    float uv = accu[rf][cf][j] * us;
                    float s = 1.f / (1.f + __expf(-gv));
                    h_ws[(size_t)(base + row0 + row) * I_ + col] = f2bf(gv * s * uv);
                }
            }
        }
    }
}

__global__ __launch_bounds__(256) void gemm2_kernel(
    const short* __restrict__ h_ws, const int* __restrict__ wq,
    const float* __restrict__ dscale,
    const int* __restrict__ cnt, const int* __restrict__ off,
    const int* __restrict__ toks, const float* __restrict__ wts,
    float* __restrict__ out) {
    int e = blockIdx.z;
    int cn = cnt[e];
    int row0 = blockIdx.y * 128;
    if (row0 >= cn) return;
    int base = off[e];
    int c0 = blockIdx.x * 128;
    __shared__ __align__(16) short As[4][128][8];
    __shared__ __align__(16) short Bs[4][128][8];
    __shared__ int stok[128];
    __shared__ float swt[128];
    int tid = threadIdx.x;
    if (tid < 128) {
        int r = row0 + tid;
        int idx = base + (r < cn ? r : 0);
        stok[tid] = toks[idx];
        swt[tid] = (r < cn) ? wts[idx] : 0.f;
    }
    __syncthreads();
    const int lane = tid & 63;
    const int wid = tid >> 6;
    const int wrow = (wid >> 1) * 64;
    const int wcc = (wid & 1) * 64;
    const int fr = lane & 15;
    const int kg = lane >> 4;
    f32x4 acc[4][4];
    #pragma unroll
    for (int i = 0; i < 4; ++i)
        #pragma unroll
        for (int j = 0; j < 4; ++j) acc[i][j] = f32x4{0.f, 0.f, 0.f, 0.f};
    const int ar = tid & 127;
    const int akg = (tid >> 7) * 2;
    const int bc = tid & 127;
    const int bkg2 = (tid >> 7) * 2;
    const short* hrow = h_ws + (size_t)(base + ((row0 + ar) < cn ? row0 + ar : 0)) * I_;
    const int* wcol = wq + (size_t)e * I_ * H_ + c0 + bc;
    for (int kk = 0; kk < I_; kk += 32) {
        #pragma unroll
        for (int p = 0; p < 2; ++p) {
            *(bf16x8*)&As[akg + p][ar][0] = *(const bf16x8*)(hrow + kk + (akg + p) * 8);
        }
        #pragma unroll
        for (int p = 0; p < 2; ++p) {
            const int* wp = wcol + (size_t)(kk + (bkg2 + p) * 8) * H_;
            bf16x8 v;
            #pragma unroll
            for (int j = 0; j < 8; ++j) v[j] = f2bf((float)wp[(size_t)j * H_] - 128.f);
            *(bf16x8*)&Bs[bkg2 + p][bc][0] = v;
        }
        __syncthreads();
        bf16x8 a[4], b[4];
        #pragma unroll
        for (int rf = 0; rf < 4; ++rf) a[rf] = *(const bf16x8*)&As[kg][wrow + rf * 16 + fr][0];
        #pragma unroll
        for (int cf = 0; cf < 4; ++cf) b[cf] = *(const bf16x8*)&Bs[kg][wcc + cf * 16 + fr][0];
        #pragma unroll
        for (int rf = 0; rf < 4; ++rf)
            #pragma unroll
            for (int cf = 0; cf < 4; ++cf)
                acc[rf][cf] = __builtin_amdgcn_mfma_f32_16x16x32_bf16(a[rf], b[cf], acc[rf][cf], 0, 0, 0);
        __syncthreads();
    }
    const int q4 = lane >> 4;
    #pragma unroll
    for (int cf = 0; cf < 4; ++cf) {
        int col = c0 + wcc + cf * 16 + fr;
        float ds = dscale[e * H_ + col];
        #pragma unroll
        for (int rf = 0; rf < 4; ++rf) {
            #pragma unroll
            for (int j = 0; j < 4; ++j) {
                int row = wrow + rf * 16 + q4 * 4 + j;
                if (row0 + row < cn) {
                    float v = acc[rf][cf][j] * ds * swt[row];
                    atomicAdd(&out[(size_t)stok[row] * H_ + col], v);
                }
            }
        }
    }
}

extern "C" void kernel_launch(void* const* d_in, const int* in_sizes, int n_in,
                              void* d_out, int out_size, void* d_ws, size_t ws_size,
                              hipStream_t stream) {
    const float* x     = (const float*)d_in[0];
    const float* aff   = (const float*)d_in[1];
    const int*   guq   = (const int*)d_in[2];
    const float* gus   = (const float*)d_in[3];
    const int*   dwq   = (const int*)d_in[4];
    const float* dsc   = (const float*)d_in[5];
    const int*   eidx  = (const int*)d_in[6];
    float* out = (float*)d_out;

    char* ws = (char*)d_ws;
    int*   cnt  = (int*)ws;                      // 8
    int*   poff = cnt + 8;                       // 8
    int*   nrbG = cnt + 16;                      // 1
    int*   rbE  = cnt + 32;                      // 64
    int*   toks = (int*)(ws + 1024);             // 10240
    float* wts  = (float*)(ws + 1024 + NRBMAX_ * 256 * 4);
    int*   inv  = (int*)(ws + 1024 + NRBMAX_ * 256 * 8);   // 8192

    const size_t off_h  = (size_t)1 << 20;
    const size_t sz_h   = (size_t)NRBMAX_ * HPBLK_ * 2;     // 36.7 MB
    const size_t off_xg = off_h + sz_h;
    const size_t sz_xg  = (size_t)NRBMAX_ * XGBLK_ * 2;     // 83.9 MB (xg, reused as dscr)
    const size_t off_gu = off_xg + sz_xg;
    const size_t sz_gu  = (size_t)E_ * 512 * TWOI_ * 8 * 2; // 234.9 MB
    const size_t off_dn = off_gu + sz_gu;
    const size_t sz_dn  = (size_t)E_ * 224 * H_ * 8 * 2;    // 117.4 MB
    const size_t NEED   = off_dn + sz_dn;                   // ~474 MB

    short* h_pk = (short*)(ws + off_h);

    route_kernel<<<1, 1024, 0, stream>>>(eidx, aff, cnt, poff, rbE, nrbG, toks, wts, inv);

    if (ws_size >= NEED) {
        short* xg   = (short*)(ws + off_xg);    // also dscr after gemm1r
        short* wgur = (short*)(ws + off_gu);
        short* wdr  = (short*)(ws + off_dn);

        gather_x_kernel<<<NRBMAX_ * 8, 256, 0, stream>>>(x, toks, nrbG, xg);
        dim3 rg1(TWOI_ / 32, H_ / 64, E_);
        repack_gu_kernel<<<rg1, 256, 0, stream>>>(guq, wgur);
        dim3 rg2(H_ / 32, I_ / 64, E_);
        repack_dn_kernel<<<rg2, 256, 0, stream>>>(dwq, wdr);

        gemm1r_kernel<<<14 * NRBMAX_, 512, 0, stream>>>(xg, wgur, gus, rbE, nrbG, h_pk);
        // xg dead; reuse as dscr
        gemm2s_kernel<<<16 * NRBMAX_, 512, 0, stream>>>(h_pk, wdr, dsc, rbE, nrbG, wts, xg);
        combine_kernel<<<(T_ * H_ / 8) / 256, 256, 0, stream>>>(xg, inv, out);
    } else {
        hipMemsetAsync(d_out, 0, (size_t)out_size * sizeof(float), stream);
        dim3 g1(I_ / 64, NSLOT_ / 128, E_);
        gemm1_kernel<<<g1, 256, 0, stream>>>(x, guq, gus, cnt, poff, toks, h_pk);
        dim3 g2(H_ / 128, NSLOT_ / 128, E_);
        gemm2_kernel<<<g2, 256, 0, stream>>>(h_pk, dwq, dsc, cnt, poff, toks, wts, out);
    }
}